// Round 9
// baseline (306.574 us; speedup 1.0000x reference)
//
#include <hip/hip_runtime.h>

// ---------------- problem constants ----------------
#define B_    2
#define Q_    2048
#define HID_  2048
#define HQ_   16
#define HKV_  4
#define D_    128
// softmax scale folded into q, in exp2 domain: D^-0.5 * log2(e)
#define QSC_  (0.08838834764831843f * 1.4426950408889634f)
#define LOG2_THETA 19.931568569324174f // log2(1e6)
// fixed softmax max: |score*log2e| <= sqrt(128)*1.4427 = 16.33 < 20 (RMSNorm'd q,k)
#define FMAX_ 20.0f

typedef unsigned short u16;
typedef __attribute__((ext_vector_type(8))) short bf16x8;
typedef __attribute__((ext_vector_type(4))) float f32x4;

__device__ __forceinline__ u16 f2bf(float x) {           // round-nearest-even
  union { float f; unsigned int u; } v; v.f = x;
  unsigned int r = v.u + 0x7FFFu + ((v.u >> 16) & 1u);
  return (u16)(r >> 16);
}
__device__ __forceinline__ u16 f2bf_t(float x) {         // truncate (hot loop)
  union { float f; unsigned int u; } v; v.f = x;
  return (u16)(v.u >> 16);
}

// async global->LDS, 16B per lane; lds must be the wave-uniform base
__device__ __forceinline__ void gl2lds16(u16* lds, const u16* g) {
  __builtin_amdgcn_global_load_lds((const __attribute__((address_space(1))) void*)g,
                                   (__attribute__((address_space(3))) void*)lds,
                                   16, 0, 0);
}

// ------- fused fp32->bf16 casts (hidden, wqkv, wo) + RoPE cos/sin table -----
#define N4_HID  2097152
#define N4_WQKV 1572864
#define N4_WO   1048576
#define N4_ALL  (N4_HID + N4_WQKV + N4_WO)     // 4718592 = 18432*256
#define NROPE   (B_ * Q_ * 64)                 // 262144  = 1024*256
__global__ __launch_bounds__(256) void cvt_all(const float* __restrict__ h,
                                               const float* __restrict__ wq,
                                               const float* __restrict__ wo,
                                               const int* __restrict__ pos,
                                               u16* __restrict__ oh,
                                               u16* __restrict__ owq,
                                               u16* __restrict__ owo,
                                               float* __restrict__ rope) {
  int i = blockIdx.x * 256 + threadIdx.x;
  if (i >= N4_ALL) {                            // RoPE table part
    int j = i - N4_ALL;                         // < NROPE
    int d = j & 63, row = j >> 6;
    float p = (float)pos[row];
    float inv = exp2f(-(float)d * (LOG2_THETA / 64.f));
    float sn, cn;
    sincosf(p * inv, &sn, &cn);
    ((float2*)rope)[j] = make_float2(cn, sn);
    return;
  }
  const float* src; u16* dst; int off;
  if (i < N4_HID)                 { src = h;  dst = oh;  off = i; }
  else if (i < N4_HID + N4_WQKV)  { src = wq; dst = owq; off = i - N4_HID; }
  else                            { src = wo; dst = owo; off = i - N4_HID - N4_WQKV; }
  float4 v = *(const float4*)(src + (size_t)off * 4);
  ushort4 o;
  o.x = f2bf(v.x); o.y = f2bf(v.y); o.z = f2bf(v.z); o.w = f2bf(v.w);
  *(ushort4*)(dst + (size_t)off * 4) = o;
}

// ------- fused QKV GEMM (256x256 8-phase) + RMSNorm + RoPE + layout ---------
// (unchanged from round 3 -- verified, bank-conflict-free)
__global__ __launch_bounds__(512) void gemm_qkv8(const u16* __restrict__ A,
                                                 const u16* __restrict__ Bw,
                                                 const float* __restrict__ rope,
                                                 const float* __restrict__ qw,
                                                 const float* __restrict__ kw,
                                                 u16* __restrict__ qb,
                                                 u16* __restrict__ kb,
                                                 u16* __restrict__ vt) {
  __shared__ __align__(16) u16 lds[65536];
  const int tid = threadIdx.x;
  const int wv = tid >> 6, lane = tid & 63;
  const int wm = wv >> 1, wn = wv & 1;             // 4M x 2N
  const int c = lane & 15, quad = lane >> 4;
  const int m0 = blockIdx.x * 256;
  const int by = blockIdx.y;
  const int n0 = by * 256;
  const int xg = ((lane & 7) ^ (lane >> 3)) * 8;   // staging source swizzle
  const int x0 = ((quad)     ^ (c & 7)) * 8;       // read swizzle, ks=0
  const int x1 = ((quad | 4) ^ (c & 7)) * 8;       // read swizzle, ks=1
  const int aoff = (wm >> 1) * 8192 + (wm & 1) * 4096 + c * 64;
  const int boff = 32768 + wn * 8192 + c * 64;
  const u16* Ag = A  + (size_t)m0 * HID_;
  const u16* Bg = Bw + (size_t)n0 * HID_;
  const int NIT = HID_ >> 7;                       // 16

#define STGQ(base, g, h, kt, buf)                                             \
  { _Pragma("unroll")                                                         \
    for (int j = 0; j < 2; ++j) {                                             \
      const int s = j * 8 + wv;                                               \
      gl2lds16(lds + (base) + (buf) * 16384 + (h) * 8192 + s * 512,           \
               (g) + (size_t)((h) * 128 + s * 8 + (lane >> 3)) * HID_         \
                   + (kt) * 64 + xg);                                         \
    } }
#define STGQ_A(h, kt, buf) STGQ(0,     Ag, h, kt, buf)
#define STGQ_B(h, kt, buf) STGQ(32768, Bg, h, kt, buf)
#define BARQ()  asm volatile("s_barrier" ::: "memory")
#define WLGQ()  { asm volatile("s_waitcnt lgkmcnt(0)" ::: "memory");          \
                  __builtin_amdgcn_sched_barrier(0); }
#define WVMQ(n) { asm volatile("s_waitcnt vmcnt(" #n ")" ::: "memory");       \
                  __builtin_amdgcn_sched_barrier(0); }
#define MMQ(MF, NF, FA, MI) {                                                 \
  acc[MF][NF] = __builtin_amdgcn_mfma_f32_16x16x32_bf16(FA[MI][0], fB[(NF)&3][0], \
                                                        acc[MF][NF], 0, 0, 0);\
  acc[MF][NF] = __builtin_amdgcn_mfma_f32_16x16x32_bf16(FA[MI][1], fB[(NF)&3][1], \
                                                        acc[MF][NF], 0, 0, 0); }

  f32x4 acc[4][8] = {};
  bf16x8 fAa[2][2], fAb[2][2], fB[4][2];

  STGQ_A(0, 0, 0); STGQ_A(1, 0, 0); STGQ_B(0, 0, 0); STGQ_B(1, 0, 0);
  STGQ_A(0, 1, 1); STGQ_B(0, 1, 1);
  WVMQ(4);
  BARQ();

#pragma unroll 1
  for (int it = 0; it < NIT; ++it) {
    const bool last = (it == NIT - 1);
    const int kt1 = 2 * it + 1, kt2 = 2 * it + 2, kt3 = 2 * it + 3;

#pragma unroll
    for (int mi = 0; mi < 2; ++mi) {
      fAa[mi][0] = *(const bf16x8*)(lds + aoff + mi * 1024 + x0);
      fAa[mi][1] = *(const bf16x8*)(lds + aoff + mi * 1024 + x1);
    }
#pragma unroll
    for (int nf = 0; nf < 4; ++nf) {
      fB[nf][0] = *(const bf16x8*)(lds + boff + nf * 1024 + x0);
      fB[nf][1] = *(const bf16x8*)(lds + boff + nf * 1024 + x1);
    }
    STGQ_A(1, kt1, 1);
    BARQ(); WLGQ();
    __builtin_amdgcn_s_setprio(1);
#pragma unroll
    for (int mi = 0; mi < 2; ++mi)
#pragma unroll
      for (int nf = 0; nf < 4; ++nf) MMQ(mi, nf, fAa, mi);
    __builtin_amdgcn_s_setprio(0);
    BARQ();

#pragma unroll
    for (int mi = 0; mi < 2; ++mi) {
      fAb[mi][0] = *(const bf16x8*)(lds + aoff + (2 + mi) * 1024 + x0);
      fAb[mi][1] = *(const bf16x8*)(lds + aoff + (2 + mi) * 1024 + x1);
    }
    STGQ_B(1, kt1, 1);
    BARQ(); WLGQ();
    __builtin_amdgcn_s_setprio(1);
#pragma unroll
    for (int mi = 0; mi < 2; ++mi)
#pragma unroll
      for (int nf = 0; nf < 4; ++nf) MMQ(2 + mi, nf, fAb, mi);
    __builtin_amdgcn_s_setprio(0);
    BARQ();

#pragma unroll
    for (int nf = 0; nf < 4; ++nf) {
      fB[nf][0] = *(const bf16x8*)(lds + boff + (4 + nf) * 1024 + x0);
      fB[nf][1] = *(const bf16x8*)(lds + boff + (4 + nf) * 1024 + x1);
    }
    if (!last) STGQ_A(0, kt2, 0);
    BARQ(); WLGQ();
    __builtin_amdgcn_s_setprio(1);
#pragma unroll
    for (int mi = 0; mi < 2; ++mi)
#pragma unroll
      for (int nf = 4; nf < 8; ++nf) MMQ(2 + mi, nf, fAb, mi);
    __builtin_amdgcn_s_setprio(0);
    BARQ();

    if (!last) STGQ_B(0, kt2, 0);
    BARQ(); WLGQ();
    __builtin_amdgcn_s_setprio(1);
#pragma unroll
    for (int mi = 0; mi < 2; ++mi)
#pragma unroll
      for (int nf = 4; nf < 8; ++nf) MMQ(mi, nf, fAa, mi);
    __builtin_amdgcn_s_setprio(0);
    if (last) { WVMQ(0); } else { WVMQ(4); }
    BARQ();

#pragma unroll
    for (int mi = 0; mi < 2; ++mi) {
      fAa[mi][0] = *(const bf16x8*)(lds + 16384 + aoff + mi * 1024 + x0);
      fAa[mi][1] = *(const bf16x8*)(lds + 16384 + aoff + mi * 1024 + x1);
    }
#pragma unroll
    for (int nf = 0; nf < 4; ++nf) {
      fB[nf][0] = *(const bf16x8*)(lds + 16384 + boff + nf * 1024 + x0);
      fB[nf][1] = *(const bf16x8*)(lds + 16384 + boff + nf * 1024 + x1);
    }
    if (!last) STGQ_A(1, kt2, 0);
    BARQ(); WLGQ();
    __builtin_amdgcn_s_setprio(1);
#pragma unroll
    for (int mi = 0; mi < 2; ++mi)
#pragma unroll
      for (int nf = 0; nf < 4; ++nf) MMQ(mi, nf, fAa, mi);
    __builtin_amdgcn_s_setprio(0);
    BARQ();

#pragma unroll
    for (int mi = 0; mi < 2; ++mi) {
      fAb[mi][0] = *(const bf16x8*)(lds + 16384 + aoff + (2 + mi) * 1024 + x0);
      fAb[mi][1] = *(const bf16x8*)(lds + 16384 + aoff + (2 + mi) * 1024 + x1);
    }
    if (!last) STGQ_B(1, kt2, 0);
    BARQ(); WLGQ();
    __builtin_amdgcn_s_setprio(1);
#pragma unroll
    for (int mi = 0; mi < 2; ++mi)
#pragma unroll
      for (int nf = 0; nf < 4; ++nf) MMQ(2 + mi, nf, fAb, mi);
    __builtin_amdgcn_s_setprio(0);
    BARQ();

#pragma unroll
    for (int nf = 0; nf < 4; ++nf) {
      fB[nf][0] = *(const bf16x8*)(lds + 16384 + boff + (4 + nf) * 1024 + x0);
      fB[nf][1] = *(const bf16x8*)(lds + 16384 + boff + (4 + nf) * 1024 + x1);
    }
    if (!last) STGQ_A(0, kt3, 1);
    BARQ(); WLGQ();
    __builtin_amdgcn_s_setprio(1);
#pragma unroll
    for (int mi = 0; mi < 2; ++mi)
#pragma unroll
      for (int nf = 4; nf < 8; ++nf) MMQ(2 + mi, nf, fAb, mi);
    __builtin_amdgcn_s_setprio(0);
    BARQ();

    if (!last) STGQ_B(0, kt3, 1);
    BARQ(); WLGQ();
    __builtin_amdgcn_s_setprio(1);
#pragma unroll
    for (int mi = 0; mi < 2; ++mi)
#pragma unroll
      for (int nf = 4; nf < 8; ++nf) MMQ(mi, nf, fAa, mi);
    __builtin_amdgcn_s_setprio(0);
    if (last) { WVMQ(0); } else { WVMQ(4); }
    BARQ();
  }

  const int h = by * 2 + wn;
  if (h < 20) {
    const bool isq = h < 16;
    const float* w = isq ? qw : kw;
    const float osc = isq ? QSC_ : 1.f;
    float wl[8];
#pragma unroll
    for (int nf = 0; nf < 8; ++nf) wl[nf] = w[nf * 16 + c];
    u16* dstbuf = isq ? qb : kb;
    const int hbase = isq ? h : (h - 16);
    const int nheads = isq ? HQ_ : HKV_;
    u16* lw = lds + wv * 4224;                   // 32 rows x stride 132
#pragma unroll
    for (int pass = 0; pass < 2; ++pass) {
#pragma unroll
      for (int mi = 0; mi < 2; ++mi) {
        const int mf = pass * 2 + mi;
#pragma unroll
        for (int r = 0; r < 4; ++r) {
          const int row = m0 + wm * 64 + mf * 16 + quad * 4 + r;
          const int q = row & (Q_ - 1), b = row >> 11;
          float ss = 0.f;
#pragma unroll
          for (int nf = 0; nf < 8; ++nf) ss += acc[mf][nf][r] * acc[mf][nf][r];
          ss += __shfl_xor(ss, 1); ss += __shfl_xor(ss, 2);
          ss += __shfl_xor(ss, 4); ss += __shfl_xor(ss, 8);
          const float rn = rsqrtf(ss * (1.f / 128.f) + 1e-6f) * osc;
          u16* lrow = lw + (mi * 16 + quad * 4 + r) * 132;
#pragma unroll
          for (int ni = 0; ni < 4; ni++) {
            float2 cssn = *(const float2*)(rope +
                ((size_t)(b * Q_ + q) * 64 + ni * 16 + c) * 2);
            float x1 = acc[mf][ni][r]     * wl[ni]     * rn;
            float x2 = acc[mf][ni + 4][r] * wl[ni + 4] * rn;
            lrow[ni * 16 + c]       = f2bf(x1 * cssn.x - x2 * cssn.y);
            lrow[(ni + 4) * 16 + c] = f2bf(x2 * cssn.x + x1 * cssn.y);
          }
        }
      }
#pragma unroll
      for (int itr = 0; itr < 8; ++itr) {
        const int rl = itr * 4 + quad;           // 0..31
        const int rowg = m0 + wm * 64 + pass * 32 + rl;
        const int q = rowg & (Q_ - 1), b = rowg >> 11;
        u16* dst = dstbuf + (((size_t)(b * nheads) + hbase) * Q_ + q) * D_ + c * 8;
        *(bf16x8*)dst = *(const bf16x8*)(lw + rl * 132 + c * 8);
      }
    }
  } else {
    const int hk = h - 20;
    const int bb = m0 >> 11;
    const int q0w = (m0 & (Q_ - 1)) + wm * 64;
    u16* lw = lds + wv * 4352;                   // 64 d-rows x stride 68
#pragma unroll
    for (int pass = 0; pass < 2; ++pass) {
#pragma unroll
      for (int nfl = 0; nfl < 4; ++nfl) {
        const int nf = pass * 4 + nfl;
#pragma unroll
        for (int mf = 0; mf < 4; ++mf) {
          short4 pv;
          pv.x = (short)f2bf(acc[mf][nf][0]); pv.y = (short)f2bf(acc[mf][nf][1]);
          pv.z = (short)f2bf(acc[mf][nf][2]); pv.w = (short)f2bf(acc[mf][nf][3]);
          *(short4*)(lw + (nfl * 16 + c) * 68 + mf * 16 + quad * 4) = pv;
        }
      }
#pragma unroll
      for (int itr = 0; itr < 8; ++itr) {
        const int dl = itr * 8 + (lane >> 3);    // 0..63
        const int d = pass * 64 + dl;
        u16* dst = vt + (((size_t)(bb * HKV_) + hk) * D_ + d) * Q_ +
                   q0w + (lane & 7) * 8;
        *(bf16x8*)dst = *(const bf16x8*)(lw + dl * 68 + (lane & 7) * 8);
      }
    }
  }
#undef STGQ
#undef STGQ_A
#undef STGQ_B
#undef BARQ
#undef WLGQ
#undef WVMQ
#undef MMQ
}

// ------------- bf16 GEMM, 128x256 tile, 8-phase counted-vmcnt schedule ------
// (unchanged from round 5 -- verified; grid 256 = 100% CU fill)
__global__ __launch_bounds__(512) void gemm_bt8(const u16* __restrict__ A,
                                                const u16* __restrict__ Bw,
                                                float* __restrict__ C,
                                                int M, int N, int K) {
  __shared__ __align__(16) u16 lds[49152];
  const int tid = threadIdx.x;
  const int wv = tid >> 6, lane = tid & 63;
  const int wm = wv >> 2, wn = wv & 3;             // 2M x 4N
  const int c = lane & 15, quad = lane >> 4;
  const int m0 = blockIdx.x * 128, n0 = blockIdx.y * 256;
  const int xg = ((lane & 7) ^ (lane >> 3)) * 8;   // staging source swizzle
  const int x0 = ((quad)     ^ (c & 7)) * 8;       // read swizzle, ks=0
  const int x1 = ((quad | 4) ^ (c & 7)) * 8;       // read swizzle, ks=1
  const int aoff = wm * 4096 + c * 64;                                  // +buf*8192
  const int boff = 16384 + (wn >> 1) * 8192 + (wn & 1) * 4096 + c * 64; // +buf*16384
  const u16* Ag = A  + (size_t)m0 * K;
  const u16* Bg = Bw + (size_t)n0 * K;
  const int NIT = K >> 7;                          // 16

#define STA2(h, kt, buf)                                                      \
  gl2lds16(lds + (buf) * 8192 + (h) * 4096 + wv * 512,                        \
           Ag + (size_t)((h) * 64 + wv * 8 + (lane >> 3)) * K + (kt) * 64 + xg);
#define STB2(h, kt, buf)                                                      \
  { _Pragma("unroll")                                                         \
    for (int j = 0; j < 2; ++j)                                               \
      gl2lds16(lds + 16384 + (buf) * 16384 + (h) * 8192 + j * 4096 + wv * 512,\
               Bg + (size_t)((h) * 128 + j * 64 + wv * 8 + (lane >> 3)) * K   \
                   + (kt) * 64 + xg); }
#define BAR8()  asm volatile("s_barrier" ::: "memory")
#define WLG8()  { asm volatile("s_waitcnt lgkmcnt(0)" ::: "memory");          \
                  __builtin_amdgcn_sched_barrier(0); }
#define WVM8(n) { asm volatile("s_waitcnt vmcnt(" #n ")" ::: "memory");       \
                  __builtin_amdgcn_sched_barrier(0); }
#define MM2(MF, NF, FA, FB, MI, NI) {                                         \
  acc[MF][NF] = __builtin_amdgcn_mfma_f32_16x16x32_bf16(FA[MI][0], FB[NI][0], \
                                                        acc[MF][NF], 0, 0, 0);\
  acc[MF][NF] = __builtin_amdgcn_mfma_f32_16x16x32_bf16(FA[MI][1], FB[NI][1], \
                                                        acc[MF][NF], 0, 0, 0); }

  f32x4 acc[4][4] = {};
  bf16x8 fAa[2][2], fAb[2][2], fBa[2][2], fBb[2][2];

  // prologue: c0 -> buf0 (6 loads), c1 -> buf1 (6); wait c0, leave c1 flying
  STA2(0, 0, 0); STA2(1, 0, 0); STB2(0, 0, 0); STB2(1, 0, 0);
  STA2(0, 1, 1); STA2(1, 1, 1); STB2(0, 1, 1); STB2(1, 1, 1);
  WVM8(6);
  BAR8();

#pragma unroll 1
  for (int it = 0; it < NIT; ++it) {
    const bool last = (it == NIT - 1);
    const int kt2 = 2 * it + 2, kt3 = 2 * it + 3;

    // ================= first half: compute K-tile 2it from buf0 ===========
#pragma unroll
    for (int mi = 0; mi < 2; ++mi) {
      fAa[mi][0] = *(const bf16x8*)(lds + aoff + mi * 1024 + x0);
      fAa[mi][1] = *(const bf16x8*)(lds + aoff + mi * 1024 + x1);
      fBa[mi][0] = *(const bf16x8*)(lds + boff + mi * 1024 + x0);
      fBa[mi][1] = *(const bf16x8*)(lds + boff + mi * 1024 + x1);
    }
    BAR8(); WLG8();
    __builtin_amdgcn_s_setprio(1);
    MM2(0, 0, fAa, fBa, 0, 0); MM2(0, 1, fAa, fBa, 0, 1);
    MM2(1, 0, fAa, fBa, 1, 0); MM2(1, 1, fAa, fBa, 1, 1);
    __builtin_amdgcn_s_setprio(0);
    BAR8();

#pragma unroll
    for (int mi = 0; mi < 2; ++mi) {
      fAb[mi][0] = *(const bf16x8*)(lds + aoff + (2 + mi) * 1024 + x0);
      fAb[mi][1] = *(const bf16x8*)(lds + aoff + (2 + mi) * 1024 + x1);
    }
    BAR8(); WLG8();
    __builtin_amdgcn_s_setprio(1);
    MM2(2, 0, fAb, fBa, 0, 0); MM2(2, 1, fAb, fBa, 0, 1);
    MM2(3, 0, fAb, fBa, 1, 0); MM2(3, 1, fAb, fBa, 1, 1);
    __builtin_amdgcn_s_setprio(0);
    BAR8();

#pragma unroll
    for (int ni = 0; ni < 2; ++ni) {
      fBb[ni][0] = *(const bf16x8*)(lds + boff + (2 + ni) * 1024 + x0);
      fBb[ni][1] = *(const bf16x8*)(lds + boff + (2 + ni) * 1024 + x1);
    }
    if (!last) { STA2(0, kt2, 0); STA2(1, kt2, 0); }
    BAR8(); WLG8();
    __builtin_amdgcn_s_setprio(1);
    MM2(2, 2, fAb, fBb, 0, 0); MM2(2, 3, fAb, fBb, 0, 1);
    MM2(3, 2, fAb, fBb, 1, 0); MM2(3, 3, fAb, fBb, 1, 1);
    __builtin_amdgcn_s_setprio(0);
    BAR8();

    if (!last) { STB2(0, kt2, 0); STB2(1, kt2, 0); }
    BAR8(); WLG8();
    __builtin_amdgcn_s_setprio(1);
    MM2(0, 2, fAa, fBb, 0, 0); MM2(0, 3, fAa, fBb, 0, 1);
    MM2(1, 2, fAa, fBb, 1, 0); MM2(1, 3, fAa, fBb, 1, 1);
    __builtin_amdgcn_s_setprio(0);
    if (last) { WVM8(0); } else { WVM8(6); }     // c1 fully landed past here
    BAR8();

    // ================= second half: compute K-tile 2it+1 from buf1 =========
#pragma unroll
    for (int mi = 0; mi < 2; ++mi) {
      fAa[mi][0] = *(const bf16x8*)(lds + 8192 + aoff + mi * 1024 + x0);
      fAa[mi][1] = *(const bf16x8*)(lds + 8192 + aoff + mi * 1024 + x1);
      fBa[mi][0] = *(const bf16x8*)(lds + 16384 + boff + mi * 1024 + x0);
      fBa[mi][1] = *(const bf16x8*)(lds + 16384 + boff + mi * 1024 + x1);
    }
    BAR8(); WLG8();
    __builtin_amdgcn_s_setprio(1);
    MM2(0, 0, fAa, fBa, 0, 0); MM2(0, 1, fAa, fBa, 0, 1);
    MM2(1, 0, fAa, fBa, 1, 0); MM2(1, 1, fAa, fBa, 1, 1);
    __builtin_amdgcn_s_setprio(0);
    BAR8();

#pragma unroll
    for (int mi = 0; mi < 2; ++mi) {
      fAb[mi][0] = *(const bf16x8*)(lds + 8192 + aoff + (2 + mi) * 1024 + x0);
      fAb[mi][1] = *(const bf16x8*)(lds + 8192 + aoff + (2 + mi) * 1024 + x1);
    }
    BAR8(); WLG8();
    __builtin_amdgcn_s_setprio(1);
    MM2(2, 0, fAb, fBa, 0, 0); MM2(2, 1, fAb, fBa, 0, 1);
    MM2(3, 0, fAb, fBa, 1, 0); MM2(3, 1, fAb, fBa, 1, 1);
    __builtin_amdgcn_s_setprio(0);
    BAR8();

#pragma unroll
    for (int ni = 0; ni < 2; ++ni) {
      fBb[ni][0] = *(const bf16x8*)(lds + 16384 + boff + (2 + ni) * 1024 + x0);
      fBb[ni][1] = *(const bf16x8*)(lds + 16384 + boff + (2 + ni) * 1024 + x1);
    }
    if (!last) { STA2(0, kt3, 1); STA2(1, kt3, 1); }
    BAR8(); WLG8();
    __builtin_amdgcn_s_setprio(1);
    MM2(2, 2, fAb, fBb, 0, 0); MM2(2, 3, fAb, fBb, 0, 1);
    MM2(3, 2, fAb, fBb, 1, 0); MM2(3, 3, fAb, fBb, 1, 1);
    __builtin_amdgcn_s_setprio(0);
    BAR8();

    if (!last) { STB2(0, kt3, 1); STB2(1, kt3, 1); }
    BAR8(); WLG8();
    __builtin_amdgcn_s_setprio(1);
    MM2(0, 2, fAa, fBb, 0, 0); MM2(0, 3, fAa, fBb, 0, 1);
    MM2(1, 2, fAa, fBb, 1, 0); MM2(1, 3, fAa, fBb, 1, 1);
    __builtin_amdgcn_s_setprio(0);
    if (last) { WVM8(0); } else { WVM8(6); }     // c2 fully landed past here
    BAR8();
  }

  // ---- epilogue: fp32 C write --------------------------------------------
  const int crow = m0 + wm * 64 + quad * 4;
  const int ccol = n0 + wn * 64 + c;
#pragma unroll
  for (int mf = 0; mf < 4; ++mf)
#pragma unroll
    for (int nf = 0; nf < 4; ++nf)
#pragma unroll
      for (int r = 0; r < 4; ++r)
        C[(size_t)(crow + mf * 16 + r) * N + ccol + nf * 16] = acc[mf][nf][r];
#undef STA2
#undef STB2
#undef BAR8
#undef WLG8
#undef WVM8
#undef MM2
}

// ------ flash attention, causal, GQA; fixed-max softmax (RMSNorm bound) -----
// v5: unpaired 128-row strips -> grid 512 (was 256 = 1 block/CU, the real
// occupancy binder v3/v4 missed). LDS cut 80->48KB via T14 reg-prefetch
// single-buffer (guarantees 2 blocks/CU): per k-tile, lanes glb-load their
// 16B chunks (same pre-swizzled sources the DMA used) into 32 VGPRs, then
// raw s_barrier (readers of kt-1 done) -> ds_write same linear layout ->
// issue kt+1 loads (fly under compute) -> lgkmcnt(0)+s_barrier (writes
// visible; wait BEFORE barrier). Raw barriers only: __syncthreads would
// drain the in-flight prefetch. Reads/P/mask/epilogue identical to v4.
// Race-safety note: all ds_read results are consumed by MFMAs before loop
// bottom (compiler-inserted lgkmcnt waits), so no wave crosses the loop-top
// barrier with pending K/V reads.
__global__ __launch_bounds__(256) void attn_fwd(const u16* __restrict__ qb,
                                                const u16* __restrict__ kb,
                                                const u16* __restrict__ vt,
                                                u16* __restrict__ ob) {
  __shared__ __align__(16) u16 lds[24576];  // K 16KB @0, V 16KB @8192, P 16KB @16384
  const int t = 15 - blockIdx.x;            // long strips launch first
  const int h = blockIdx.y, b = blockIdx.z;
  const int hk = h >> 2;
  const int tid = threadIdx.x, wave = tid >> 6, lane = tid & 63;
  const int c = lane & 15, quad = lane >> 4;
  const int lr = lane >> 2, lp = lane & 3;
  const int lpg = (lp + 4 - ((lr >> 1) & 3)) & 3;
  const int swq = ((quad + (c >> 1)) & 3) * 8;
  const int psw = (c & 7) << 3;            // P granule swizzle (u16 units)
  const u16* qg = qb + ((size_t)b * HQ_ + h) * (size_t)Q_ * D_;
  const u16* kg = kb + ((size_t)b * HKV_ + hk) * (size_t)Q_ * D_;
  const u16* vg = vt + ((size_t)b * HKV_ + hk) * (size_t)D_ * Q_;
  u16* Pw = lds + 16384 + wave * 2048;     // 32 rows x 64 u16, swizzled
  u16* Bw = lds + wave * 2176;             // epilogue bounce (K+V region, dead)

#define GLDKV(KT)                                                             \
  { _Pragma("unroll")                                                         \
    for (int i = 0; i < 4; i++) {                                             \
      kreg[i] = *(const bf16x8*)(kg + ((size_t)(KT) * 64 + wave * 16 + lr) * D_ \
                                 + i * 32 + lpg * 8);                         \
      vreg[i] = *(const bf16x8*)(vg + (size_t)((i & 1) * 64 + wave * 16 + lr) * Q_ \
                                 + (KT) * 64 + (i >> 1) * 32 + lpg * 8);      \
    } }
#define BARA()  asm volatile("s_barrier" ::: "memory")
#define WLGA()  { asm volatile("s_waitcnt lgkmcnt(0)" ::: "memory");          \
                  __builtin_amdgcn_sched_barrier(0); }
#define MFMA_A(A0, B0, C0) __builtin_amdgcn_mfma_f32_16x16x32_bf16(A0, B0, C0, 0, 0, 0)

  const int q0 = t * 128;
  const int qbase = q0 + wave * 32;
  bf16x8 qf[2][4];
#pragma unroll
  for (int qh = 0; qh < 2; qh++)
#pragma unroll
    for (int kk = 0; kk < 4; kk++)
      qf[qh][kk] = *(const bf16x8*)(qg + (size_t)(qbase + qh * 16 + c) * D_ +
                                    kk * 32 + quad * 8);
  f32x4 Oa[8][2] = {};
  float l0 = 0.f, l1 = 0.f;
  bf16x8 kreg[4], vreg[4];

  GLDKV(0);                                // prologue: kt=0 -> regs
  const int nkt = 2 * t + 2;
#pragma unroll 1
  for (int kt = 0; kt < nkt; kt++) {
    BARA();                                // all waves done reading kt-1 LDS
    // regs -> LDS (compiler inserts vmcnt wait via register dependency)
#pragma unroll
    for (int i = 0; i < 4; i++) {
      *(bf16x8*)(lds + (size_t)(i * 256 + wave * 64 + lane) * 8) = kreg[i];
      *(bf16x8*)(lds + 8192 + (size_t)(i * 256 + wave * 64 + lane) * 8) = vreg[i];
    }
    if (kt + 1 < nkt) GLDKV(kt + 1);       // prefetch flies under compute
    WLGA(); BARA();                        // my writes drained, then join
    f32x4 S[4][2];
#pragma unroll
    for (int n = 0; n < 4; n++) {
      S[n][0] = f32x4{-FMAX_, -FMAX_, -FMAX_, -FMAX_};
      S[n][1] = f32x4{-FMAX_, -FMAX_, -FMAX_, -FMAX_};
#pragma unroll
      for (int kk = 0; kk < 4; kk++) {
        bf16x8 kf = *(const bf16x8*)(lds + kk * 2048 + (n * 16 + c) * 32 + swq);
        S[n][0] = MFMA_A(kf, qf[0][kk], S[n][0]);
        S[n][1] = MFMA_A(kf, qf[1][kk], S[n][1]);
      }
    }
    if (kt >= 2 * t) {                     // possibly-masked tiles
#pragma unroll
      for (int n = 0; n < 4; n++)
#pragma unroll
        for (int qh = 0; qh < 2; qh++)
#pragma unroll
          for (int r = 0; r < 4; r++) {
            int key = kt * 64 + n * 16 + quad * 4 + r;
            if (key > qbase + qh * 16 + c) S[n][qh][r] = -1e9f;  // exp2 -> 0
          }
    }
#pragma unroll
    for (int n = 0; n < 4; n++)
#pragma unroll
      for (int qh = 0; qh < 2; qh++) {
        float p0 = __builtin_amdgcn_exp2f(S[n][qh][0]);
        float p1 = __builtin_amdgcn_exp2f(S[n][qh][1]);
        float p2 = __builtin_amdgcn_exp2f(S[n][qh][2]);
        float p3 = __builtin_amdgcn_exp2f(S[n][qh][3]);
        if (qh) l1 += (p0 + p1) + (p2 + p3);
        else    l0 += (p0 + p1) + (p2 + p3);
        short4 pk;
        pk.x = (short)f2bf_t(p0); pk.y = (short)f2bf_t(p1);
        pk.z = (short)f2bf_t(p2); pk.w = (short)f2bf_t(p3);
        *(short4*)(Pw + (qh * 16 + c) * 64 + ((n * 16 + quad * 4) ^ psw)) = pk;
      }
    bf16x8 pf[2][2];
#pragma unroll
    for (int qh = 0; qh < 2; qh++)
#pragma unroll
      for (int kk2 = 0; kk2 < 2; kk2++)
        pf[qh][kk2] = *(const bf16x8*)(Pw + (qh * 16 + c) * 64 +
                                       ((kk2 * 32 + quad * 8) ^ psw));
#pragma unroll
    for (int md = 0; md < 8; md++)
#pragma unroll
      for (int kk2 = 0; kk2 < 2; kk2++) {
        bf16x8 vf = *(const bf16x8*)(lds + 8192 + kk2 * 4096 +
                                     (md * 16 + c) * 32 + swq);
        Oa[md][0] = MFMA_A(vf, pf[0][kk2], Oa[md][0]);
        Oa[md][1] = MFMA_A(vf, pf[1][kk2], Oa[md][1]);
      }
  }
  // epilogue: reduce l, normalize, transpose via bounce, store (2 passes)
  l0 += __shfl_xor(l0, 16); l0 += __shfl_xor(l0, 32);
  l1 += __shfl_xor(l1, 16); l1 += __shfl_xor(l1, 32);
  WLGA(); BARA();                          // all K/V reads done; region = bounce
#pragma unroll
  for (int qh = 0; qh < 2; qh++) {
    const float invl = 1.f / (qh ? l1 : l0);
#pragma unroll
    for (int md = 0; md < 8; md++) {
      short4 ok;
      ok.x = (short)f2bf(Oa[md][qh][0] * invl);
      ok.y = (short)f2bf(Oa[md][qh][1] * invl);
      ok.z = (short)f2bf(Oa[md][qh][2] * invl);
      ok.w = (short)f2bf(Oa[md][qh][3] * invl);
      *(short4*)(Bw + c * 136 + md * 16 + quad * 4) = ok;
    }
    const int orow = q0 + wave * 32 + qh * 16 + lr;
#pragma unroll
    for (int tt = 0; tt < 4; tt++) {
      bf16x8 ov = *(const bf16x8*)(Bw + lr * 136 + lp * 32 + tt * 8);
      *(bf16x8*)(ob + ((size_t)(b * Q_ + orow) * HQ_ + h) * D_ + lp * 32 + tt * 8) = ov;
    }
    // WAR fence: pass-0 bounce reads must land before pass-1 overwrites
    asm volatile("s_waitcnt lgkmcnt(0)" ::: "memory");
    __builtin_amdgcn_sched_barrier(0);
  }
#undef GLDKV
#undef BARA
#undef WLGA
#undef MFMA_A
}

// ---------------- launcher ----------------
extern "C" void kernel_launch(void* const* d_in, const int* in_sizes, int n_in,
                              void* d_out, int out_size, void* d_ws, size_t ws_size,
                              hipStream_t stream) {
  const int*   positions = (const int*)  d_in[0];
  const float* hidden    = (const float*)d_in[1];
  const float* wqkv      = (const float*)d_in[4];
  const float* wo        = (const float*)d_in[5];
  const float* qnw       = (const float*)d_in[6];
  const float* knw       = (const float*)d_in[7];
  char* ws = (char*)d_ws;
  u16*   hid_bf  = (u16*)(ws);                     // 16,777,216
  u16*   wqkv_bf = (u16*)(ws + 16777216);          // 12,582,912
  u16*   wo_bf   = (u16*)(ws + 29360128);          //  8,388,608
  u16*   q_bf    = (u16*)(ws + 37748736);          // 16,777,216
  u16*   k_bf    = (u16*)(ws + 54525952);          //  4,194,304
  u16*   vt_bf   = (u16*)(ws + 58720256);          //  4,194,304
  float* rope    = (float*)(ws + 62914560);        //  2,097,152
  u16*   attn_bf = hid_bf;                         // alias: dead after gemm_qkv8

  cvt_all<<<19456, 256, 0, stream>>>(hidden, wqkv, wo, positions,
                                     hid_bf, wqkv_bf, wo_bf, rope);
  gemm_qkv8<<<dim3(16, 12), 512, 0, stream>>>(hid_bf, wqkv_bf, rope, qnw, knw,
                                              q_bf, k_bf, vt_bf);
  attn_fwd<<<dim3(16, 16, 2), 256, 0, stream>>>(q_bf, k_bf, vt_bf, attn_bf);
  gemm_bt8<<<dim3(32, 8), 512, 0, stream>>>(attn_bf, wo_bf, (float*)d_out,
                                            4096, 2048, 2048);
}

// Round 10
// 303.725 us; speedup vs baseline: 1.0094x; 1.0094x over previous
//
#include <hip/hip_runtime.h>

// ---------------- problem constants ----------------
#define B_    2
#define Q_    2048
#define HID_  2048
#define HQ_   16
#define HKV_  4
#define D_    128
// softmax scale folded into q, in exp2 domain: D^-0.5 * log2(e)
#define QSC_  (0.08838834764831843f * 1.4426950408889634f)
#define LOG2_THETA 19.931568569324174f // log2(1e6)
// fixed softmax max: |score*log2e| <= sqrt(128)*1.4427 = 16.33 < 20 (RMSNorm'd q,k)
#define FMAX_ 20.0f

typedef unsigned short u16;
typedef __attribute__((ext_vector_type(8))) short bf16x8;
typedef __attribute__((ext_vector_type(4))) float f32x4;

__device__ __forceinline__ u16 f2bf(float x) {           // round-nearest-even
  union { float f; unsigned int u; } v; v.f = x;
  unsigned int r = v.u + 0x7FFFu + ((v.u >> 16) & 1u);
  return (u16)(r >> 16);
}
__device__ __forceinline__ u16 f2bf_t(float x) {         // truncate (hot loop)
  union { float f; unsigned int u; } v; v.f = x;
  return (u16)(v.u >> 16);
}

// async global->LDS, 16B per lane; lds must be the wave-uniform base
__device__ __forceinline__ void gl2lds16(u16* lds, const u16* g) {
  __builtin_amdgcn_global_load_lds((const __attribute__((address_space(1))) void*)g,
                                   (__attribute__((address_space(3))) void*)lds,
                                   16, 0, 0);
}

// ------- fused fp32->bf16 casts (hidden, wqkv, wo) + RoPE cos/sin table -----
#define N4_HID  2097152
#define N4_WQKV 1572864
#define N4_WO   1048576
#define N4_ALL  (N4_HID + N4_WQKV + N4_WO)     // 4718592 = 18432*256
#define NROPE   (B_ * Q_ * 64)                 // 262144  = 1024*256
__global__ __launch_bounds__(256) void cvt_all(const float* __restrict__ h,
                                               const float* __restrict__ wq,
                                               const float* __restrict__ wo,
                                               const int* __restrict__ pos,
                                               u16* __restrict__ oh,
                                               u16* __restrict__ owq,
                                               u16* __restrict__ owo,
                                               float* __restrict__ rope) {
  int i = blockIdx.x * 256 + threadIdx.x;
  if (i >= N4_ALL) {                            // RoPE table part
    int j = i - N4_ALL;                         // < NROPE
    int d = j & 63, row = j >> 6;
    float p = (float)pos[row];
    float inv = exp2f(-(float)d * (LOG2_THETA / 64.f));
    float sn, cn;
    sincosf(p * inv, &sn, &cn);
    ((float2*)rope)[j] = make_float2(cn, sn);
    return;
  }
  const float* src; u16* dst; int off;
  if (i < N4_HID)                 { src = h;  dst = oh;  off = i; }
  else if (i < N4_HID + N4_WQKV)  { src = wq; dst = owq; off = i - N4_HID; }
  else                            { src = wo; dst = owo; off = i - N4_HID - N4_WQKV; }
  float4 v = *(const float4*)(src + (size_t)off * 4);
  ushort4 o;
  o.x = f2bf(v.x); o.y = f2bf(v.y); o.z = f2bf(v.z); o.w = f2bf(v.w);
  *(ushort4*)(dst + (size_t)off * 4) = o;
}

// ------- fused QKV GEMM (256x256 8-phase) + RMSNorm + RoPE + layout ---------
// (unchanged from round 3 -- verified, bank-conflict-free)
__global__ __launch_bounds__(512) void gemm_qkv8(const u16* __restrict__ A,
                                                 const u16* __restrict__ Bw,
                                                 const float* __restrict__ rope,
                                                 const float* __restrict__ qw,
                                                 const float* __restrict__ kw,
                                                 u16* __restrict__ qb,
                                                 u16* __restrict__ kb,
                                                 u16* __restrict__ vt) {
  __shared__ __align__(16) u16 lds[65536];
  const int tid = threadIdx.x;
  const int wv = tid >> 6, lane = tid & 63;
  const int wm = wv >> 1, wn = wv & 1;             // 4M x 2N
  const int c = lane & 15, quad = lane >> 4;
  const int m0 = blockIdx.x * 256;
  const int by = blockIdx.y;
  const int n0 = by * 256;
  const int xg = ((lane & 7) ^ (lane >> 3)) * 8;   // staging source swizzle
  const int x0 = ((quad)     ^ (c & 7)) * 8;       // read swizzle, ks=0
  const int x1 = ((quad | 4) ^ (c & 7)) * 8;       // read swizzle, ks=1
  const int aoff = (wm >> 1) * 8192 + (wm & 1) * 4096 + c * 64;
  const int boff = 32768 + wn * 8192 + c * 64;
  const u16* Ag = A  + (size_t)m0 * HID_;
  const u16* Bg = Bw + (size_t)n0 * HID_;
  const int NIT = HID_ >> 7;                       // 16

#define STGQ(base, g, h, kt, buf)                                             \
  { _Pragma("unroll")                                                         \
    for (int j = 0; j < 2; ++j) {                                             \
      const int s = j * 8 + wv;                                               \
      gl2lds16(lds + (base) + (buf) * 16384 + (h) * 8192 + s * 512,           \
               (g) + (size_t)((h) * 128 + s * 8 + (lane >> 3)) * HID_         \
                   + (kt) * 64 + xg);                                         \
    } }
#define STGQ_A(h, kt, buf) STGQ(0,     Ag, h, kt, buf)
#define STGQ_B(h, kt, buf) STGQ(32768, Bg, h, kt, buf)
#define BARQ()  asm volatile("s_barrier" ::: "memory")
#define WLGQ()  { asm volatile("s_waitcnt lgkmcnt(0)" ::: "memory");          \
                  __builtin_amdgcn_sched_barrier(0); }
#define WVMQ(n) { asm volatile("s_waitcnt vmcnt(" #n ")" ::: "memory");       \
                  __builtin_amdgcn_sched_barrier(0); }
#define MMQ(MF, NF, FA, MI) {                                                 \
  acc[MF][NF] = __builtin_amdgcn_mfma_f32_16x16x32_bf16(FA[MI][0], fB[(NF)&3][0], \
                                                        acc[MF][NF], 0, 0, 0);\
  acc[MF][NF] = __builtin_amdgcn_mfma_f32_16x16x32_bf16(FA[MI][1], fB[(NF)&3][1], \
                                                        acc[MF][NF], 0, 0, 0); }

  f32x4 acc[4][8] = {};
  bf16x8 fAa[2][2], fAb[2][2], fB[4][2];

  STGQ_A(0, 0, 0); STGQ_A(1, 0, 0); STGQ_B(0, 0, 0); STGQ_B(1, 0, 0);
  STGQ_A(0, 1, 1); STGQ_B(0, 1, 1);
  WVMQ(4);
  BARQ();

#pragma unroll 1
  for (int it = 0; it < NIT; ++it) {
    const bool last = (it == NIT - 1);
    const int kt1 = 2 * it + 1, kt2 = 2 * it + 2, kt3 = 2 * it + 3;

#pragma unroll
    for (int mi = 0; mi < 2; ++mi) {
      fAa[mi][0] = *(const bf16x8*)(lds + aoff + mi * 1024 + x0);
      fAa[mi][1] = *(const bf16x8*)(lds + aoff + mi * 1024 + x1);
    }
#pragma unroll
    for (int nf = 0; nf < 4; ++nf) {
      fB[nf][0] = *(const bf16x8*)(lds + boff + nf * 1024 + x0);
      fB[nf][1] = *(const bf16x8*)(lds + boff + nf * 1024 + x1);
    }
    STGQ_A(1, kt1, 1);
    BARQ(); WLGQ();
    __builtin_amdgcn_s_setprio(1);
#pragma unroll
    for (int mi = 0; mi < 2; ++mi)
#pragma unroll
      for (int nf = 0; nf < 4; ++nf) MMQ(mi, nf, fAa, mi);
    __builtin_amdgcn_s_setprio(0);
    BARQ();

#pragma unroll
    for (int mi = 0; mi < 2; ++mi) {
      fAb[mi][0] = *(const bf16x8*)(lds + aoff + (2 + mi) * 1024 + x0);
      fAb[mi][1] = *(const bf16x8*)(lds + aoff + (2 + mi) * 1024 + x1);
    }
    STGQ_B(1, kt1, 1);
    BARQ(); WLGQ();
    __builtin_amdgcn_s_setprio(1);
#pragma unroll
    for (int mi = 0; mi < 2; ++mi)
#pragma unroll
      for (int nf = 0; nf < 4; ++nf) MMQ(2 + mi, nf, fAb, mi);
    __builtin_amdgcn_s_setprio(0);
    BARQ();

#pragma unroll
    for (int nf = 0; nf < 4; ++nf) {
      fB[nf][0] = *(const bf16x8*)(lds + boff + (4 + nf) * 1024 + x0);
      fB[nf][1] = *(const bf16x8*)(lds + boff + (4 + nf) * 1024 + x1);
    }
    if (!last) STGQ_A(0, kt2, 0);
    BARQ(); WLGQ();
    __builtin_amdgcn_s_setprio(1);
#pragma unroll
    for (int mi = 0; mi < 2; ++mi)
#pragma unroll
      for (int nf = 4; nf < 8; ++nf) MMQ(2 + mi, nf, fAb, mi);
    __builtin_amdgcn_s_setprio(0);
    BARQ();

    if (!last) STGQ_B(0, kt2, 0);
    BARQ(); WLGQ();
    __builtin_amdgcn_s_setprio(1);
#pragma unroll
    for (int mi = 0; mi < 2; ++mi)
#pragma unroll
      for (int nf = 4; nf < 8; ++nf) MMQ(mi, nf, fAa, mi);
    __builtin_amdgcn_s_setprio(0);
    if (last) { WVMQ(0); } else { WVMQ(4); }
    BARQ();

#pragma unroll
    for (int mi = 0; mi < 2; ++mi) {
      fAa[mi][0] = *(const bf16x8*)(lds + 16384 + aoff + mi * 1024 + x0);
      fAa[mi][1] = *(const bf16x8*)(lds + 16384 + aoff + mi * 1024 + x1);
    }
#pragma unroll
    for (int nf = 0; nf < 4; ++nf) {
      fB[nf][0] = *(const bf16x8*)(lds + 16384 + boff + nf * 1024 + x0);
      fB[nf][1] = *(const bf16x8*)(lds + 16384 + boff + nf * 1024 + x1);
    }
    if (!last) STGQ_A(1, kt2, 0);
    BARQ(); WLGQ();
    __builtin_amdgcn_s_setprio(1);
#pragma unroll
    for (int mi = 0; mi < 2; ++mi)
#pragma unroll
      for (int nf = 0; nf < 4; ++nf) MMQ(mi, nf, fAa, mi);
    __builtin_amdgcn_s_setprio(0);
    BARQ();

#pragma unroll
    for (int mi = 0; mi < 2; ++mi) {
      fAb[mi][0] = *(const bf16x8*)(lds + 16384 + aoff + (2 + mi) * 1024 + x0);
      fAb[mi][1] = *(const bf16x8*)(lds + 16384 + aoff + (2 + mi) * 1024 + x1);
    }
    if (!last) STGQ_B(1, kt2, 0);
    BARQ(); WLGQ();
    __builtin_amdgcn_s_setprio(1);
#pragma unroll
    for (int mi = 0; mi < 2; ++mi)
#pragma unroll
      for (int nf = 0; nf < 4; ++nf) MMQ(2 + mi, nf, fAb, mi);
    __builtin_amdgcn_s_setprio(0);
    BARQ();

#pragma unroll
    for (int nf = 0; nf < 4; ++nf) {
      fB[nf][0] = *(const bf16x8*)(lds + 16384 + boff + (4 + nf) * 1024 + x0);
      fB[nf][1] = *(const bf16x8*)(lds + 16384 + boff + (4 + nf) * 1024 + x1);
    }
    if (!last) STGQ_A(0, kt3, 1);
    BARQ(); WLGQ();
    __builtin_amdgcn_s_setprio(1);
#pragma unroll
    for (int mi = 0; mi < 2; ++mi)
#pragma unroll
      for (int nf = 4; nf < 8; ++nf) MMQ(2 + mi, nf, fAb, mi);
    __builtin_amdgcn_s_setprio(0);
    BARQ();

    if (!last) STGQ_B(0, kt3, 1);
    BARQ(); WLGQ();
    __builtin_amdgcn_s_setprio(1);
#pragma unroll
    for (int mi = 0; mi < 2; ++mi)
#pragma unroll
      for (int nf = 4; nf < 8; ++nf) MMQ(mi, nf, fAa, mi);
    __builtin_amdgcn_s_setprio(0);
    if (last) { WVMQ(0); } else { WVMQ(4); }
    BARQ();
  }

  const int h = by * 2 + wn;
  if (h < 20) {
    const bool isq = h < 16;
    const float* w = isq ? qw : kw;
    const float osc = isq ? QSC_ : 1.f;
    float wl[8];
#pragma unroll
    for (int nf = 0; nf < 8; ++nf) wl[nf] = w[nf * 16 + c];
    u16* dstbuf = isq ? qb : kb;
    const int hbase = isq ? h : (h - 16);
    const int nheads = isq ? HQ_ : HKV_;
    u16* lw = lds + wv * 4224;                   // 32 rows x stride 132
#pragma unroll
    for (int pass = 0; pass < 2; ++pass) {
#pragma unroll
      for (int mi = 0; mi < 2; ++mi) {
        const int mf = pass * 2 + mi;
#pragma unroll
        for (int r = 0; r < 4; ++r) {
          const int row = m0 + wm * 64 + mf * 16 + quad * 4 + r;
          const int q = row & (Q_ - 1), b = row >> 11;
          float ss = 0.f;
#pragma unroll
          for (int nf = 0; nf < 8; ++nf) ss += acc[mf][nf][r] * acc[mf][nf][r];
          ss += __shfl_xor(ss, 1); ss += __shfl_xor(ss, 2);
          ss += __shfl_xor(ss, 4); ss += __shfl_xor(ss, 8);
          const float rn = rsqrtf(ss * (1.f / 128.f) + 1e-6f) * osc;
          u16* lrow = lw + (mi * 16 + quad * 4 + r) * 132;
#pragma unroll
          for (int ni = 0; ni < 4; ni++) {
            float2 cssn = *(const float2*)(rope +
                ((size_t)(b * Q_ + q) * 64 + ni * 16 + c) * 2);
            float x1 = acc[mf][ni][r]     * wl[ni]     * rn;
            float x2 = acc[mf][ni + 4][r] * wl[ni + 4] * rn;
            lrow[ni * 16 + c]       = f2bf(x1 * cssn.x - x2 * cssn.y);
            lrow[(ni + 4) * 16 + c] = f2bf(x2 * cssn.x + x1 * cssn.y);
          }
        }
      }
#pragma unroll
      for (int itr = 0; itr < 8; ++itr) {
        const int rl = itr * 4 + quad;           // 0..31
        const int rowg = m0 + wm * 64 + pass * 32 + rl;
        const int q = rowg & (Q_ - 1), b = rowg >> 11;
        u16* dst = dstbuf + (((size_t)(b * nheads) + hbase) * Q_ + q) * D_ + c * 8;
        *(bf16x8*)dst = *(const bf16x8*)(lw + rl * 132 + c * 8);
      }
    }
  } else {
    const int hk = h - 20;
    const int bb = m0 >> 11;
    const int q0w = (m0 & (Q_ - 1)) + wm * 64;
    u16* lw = lds + wv * 4352;                   // 64 d-rows x stride 68
#pragma unroll
    for (int pass = 0; pass < 2; ++pass) {
#pragma unroll
      for (int nfl = 0; nfl < 4; ++nfl) {
        const int nf = pass * 4 + nfl;
#pragma unroll
        for (int mf = 0; mf < 4; ++mf) {
          short4 pv;
          pv.x = (short)f2bf(acc[mf][nf][0]); pv.y = (short)f2bf(acc[mf][nf][1]);
          pv.z = (short)f2bf(acc[mf][nf][2]); pv.w = (short)f2bf(acc[mf][nf][3]);
          *(short4*)(lw + (nfl * 16 + c) * 68 + mf * 16 + quad * 4) = pv;
        }
      }
#pragma unroll
      for (int itr = 0; itr < 8; ++itr) {
        const int dl = itr * 8 + (lane >> 3);    // 0..63
        const int d = pass * 64 + dl;
        u16* dst = vt + (((size_t)(bb * HKV_) + hk) * D_ + d) * Q_ +
                   q0w + (lane & 7) * 8;
        *(bf16x8*)dst = *(const bf16x8*)(lw + dl * 68 + (lane & 7) * 8);
      }
    }
  }
#undef STGQ
#undef STGQ_A
#undef STGQ_B
#undef BARQ
#undef WLGQ
#undef WVMQ
#undef MMQ
}

// ------------- bf16 GEMM, 128x256 tile, 8-phase counted-vmcnt schedule ------
// (unchanged from round 5 -- verified; grid 256 = 100% CU fill)
__global__ __launch_bounds__(512) void gemm_bt8(const u16* __restrict__ A,
                                                const u16* __restrict__ Bw,
                                                float* __restrict__ C,
                                                int M, int N, int K) {
  __shared__ __align__(16) u16 lds[49152];
  const int tid = threadIdx.x;
  const int wv = tid >> 6, lane = tid & 63;
  const int wm = wv >> 2, wn = wv & 3;             // 2M x 4N
  const int c = lane & 15, quad = lane >> 4;
  const int m0 = blockIdx.x * 128, n0 = blockIdx.y * 256;
  const int xg = ((lane & 7) ^ (lane >> 3)) * 8;   // staging source swizzle
  const int x0 = ((quad)     ^ (c & 7)) * 8;       // read swizzle, ks=0
  const int x1 = ((quad | 4) ^ (c & 7)) * 8;       // read swizzle, ks=1
  const int aoff = wm * 4096 + c * 64;                                  // +buf*8192
  const int boff = 16384 + (wn >> 1) * 8192 + (wn & 1) * 4096 + c * 64; // +buf*16384
  const u16* Ag = A  + (size_t)m0 * K;
  const u16* Bg = Bw + (size_t)n0 * K;
  const int NIT = K >> 7;                          // 16

#define STA2(h, kt, buf)                                                      \
  gl2lds16(lds + (buf) * 8192 + (h) * 4096 + wv * 512,                        \
           Ag + (size_t)((h) * 64 + wv * 8 + (lane >> 3)) * K + (kt) * 64 + xg);
#define STB2(h, kt, buf)                                                      \
  { _Pragma("unroll")                                                         \
    for (int j = 0; j < 2; ++j)                                               \
      gl2lds16(lds + 16384 + (buf) * 16384 + (h) * 8192 + j * 4096 + wv * 512,\
               Bg + (size_t)((h) * 128 + j * 64 + wv * 8 + (lane >> 3)) * K   \
                   + (kt) * 64 + xg); }
#define BAR8()  asm volatile("s_barrier" ::: "memory")
#define WLG8()  { asm volatile("s_waitcnt lgkmcnt(0)" ::: "memory");          \
                  __builtin_amdgcn_sched_barrier(0); }
#define WVM8(n) { asm volatile("s_waitcnt vmcnt(" #n ")" ::: "memory");       \
                  __builtin_amdgcn_sched_barrier(0); }
#define MM2(MF, NF, FA, FB, MI, NI) {                                         \
  acc[MF][NF] = __builtin_amdgcn_mfma_f32_16x16x32_bf16(FA[MI][0], FB[NI][0], \
                                                        acc[MF][NF], 0, 0, 0);\
  acc[MF][NF] = __builtin_amdgcn_mfma_f32_16x16x32_bf16(FA[MI][1], FB[NI][1], \
                                                        acc[MF][NF], 0, 0, 0); }

  f32x4 acc[4][4] = {};
  bf16x8 fAa[2][2], fAb[2][2], fBa[2][2], fBb[2][2];

  // prologue: c0 -> buf0 (6 loads), c1 -> buf1 (6); wait c0, leave c1 flying
  STA2(0, 0, 0); STA2(1, 0, 0); STB2(0, 0, 0); STB2(1, 0, 0);
  STA2(0, 1, 1); STA2(1, 1, 1); STB2(0, 1, 1); STB2(1, 1, 1);
  WVM8(6);
  BAR8();

#pragma unroll 1
  for (int it = 0; it < NIT; ++it) {
    const bool last = (it == NIT - 1);
    const int kt2 = 2 * it + 2, kt3 = 2 * it + 3;

    // ================= first half: compute K-tile 2it from buf0 ===========
#pragma unroll
    for (int mi = 0; mi < 2; ++mi) {
      fAa[mi][0] = *(const bf16x8*)(lds + aoff + mi * 1024 + x0);
      fAa[mi][1] = *(const bf16x8*)(lds + aoff + mi * 1024 + x1);
      fBa[mi][0] = *(const bf16x8*)(lds + boff + mi * 1024 + x0);
      fBa[mi][1] = *(const bf16x8*)(lds + boff + mi * 1024 + x1);
    }
    BAR8(); WLG8();
    __builtin_amdgcn_s_setprio(1);
    MM2(0, 0, fAa, fBa, 0, 0); MM2(0, 1, fAa, fBa, 0, 1);
    MM2(1, 0, fAa, fBa, 1, 0); MM2(1, 1, fAa, fBa, 1, 1);
    __builtin_amdgcn_s_setprio(0);
    BAR8();

#pragma unroll
    for (int mi = 0; mi < 2; ++mi) {
      fAb[mi][0] = *(const bf16x8*)(lds + aoff + (2 + mi) * 1024 + x0);
      fAb[mi][1] = *(const bf16x8*)(lds + aoff + (2 + mi) * 1024 + x1);
    }
    BAR8(); WLG8();
    __builtin_amdgcn_s_setprio(1);
    MM2(2, 0, fAb, fBa, 0, 0); MM2(2, 1, fAb, fBa, 0, 1);
    MM2(3, 0, fAb, fBa, 1, 0); MM2(3, 1, fAb, fBa, 1, 1);
    __builtin_amdgcn_s_setprio(0);
    BAR8();

#pragma unroll
    for (int ni = 0; ni < 2; ++ni) {
      fBb[ni][0] = *(const bf16x8*)(lds + boff + (2 + ni) * 1024 + x0);
      fBb[ni][1] = *(const bf16x8*)(lds + boff + (2 + ni) * 1024 + x1);
    }
    if (!last) { STA2(0, kt2, 0); STA2(1, kt2, 0); }
    BAR8(); WLG8();
    __builtin_amdgcn_s_setprio(1);
    MM2(2, 2, fAb, fBb, 0, 0); MM2(2, 3, fAb, fBb, 0, 1);
    MM2(3, 2, fAb, fBb, 1, 0); MM2(3, 3, fAb, fBb, 1, 1);
    __builtin_amdgcn_s_setprio(0);
    BAR8();

    if (!last) { STB2(0, kt2, 0); STB2(1, kt2, 0); }
    BAR8(); WLG8();
    __builtin_amdgcn_s_setprio(1);
    MM2(0, 2, fAa, fBb, 0, 0); MM2(0, 3, fAa, fBb, 0, 1);
    MM2(1, 2, fAa, fBb, 1, 0); MM2(1, 3, fAa, fBb, 1, 1);
    __builtin_amdgcn_s_setprio(0);
    if (last) { WVM8(0); } else { WVM8(6); }     // c1 fully landed past here
    BAR8();

    // ================= second half: compute K-tile 2it+1 from buf1 =========
#pragma unroll
    for (int mi = 0; mi < 2; ++mi) {
      fAa[mi][0] = *(const bf16x8*)(lds + 8192 + aoff + mi * 1024 + x0);
      fAa[mi][1] = *(const bf16x8*)(lds + 8192 + aoff + mi * 1024 + x1);
      fBa[mi][0] = *(const bf16x8*)(lds + 16384 + boff + mi * 1024 + x0);
      fBa[mi][1] = *(const bf16x8*)(lds + 16384 + boff + mi * 1024 + x1);
    }
    BAR8(); WLG8();
    __builtin_amdgcn_s_setprio(1);
    MM2(0, 0, fAa, fBa, 0, 0); MM2(0, 1, fAa, fBa, 0, 1);
    MM2(1, 0, fAa, fBa, 1, 0); MM2(1, 1, fAa, fBa, 1, 1);
    __builtin_amdgcn_s_setprio(0);
    BAR8();

#pragma unroll
    for (int mi = 0; mi < 2; ++mi) {
      fAb[mi][0] = *(const bf16x8*)(lds + 8192 + aoff + (2 + mi) * 1024 + x0);
      fAb[mi][1] = *(const bf16x8*)(lds + 8192 + aoff + (2 + mi) * 1024 + x1);
    }
    BAR8(); WLG8();
    __builtin_amdgcn_s_setprio(1);
    MM2(2, 0, fAb, fBa, 0, 0); MM2(2, 1, fAb, fBa, 0, 1);
    MM2(3, 0, fAb, fBa, 1, 0); MM2(3, 1, fAb, fBa, 1, 1);
    __builtin_amdgcn_s_setprio(0);
    BAR8();

#pragma unroll
    for (int ni = 0; ni < 2; ++ni) {
      fBb[ni][0] = *(const bf16x8*)(lds + 16384 + boff + (2 + ni) * 1024 + x0);
      fBb[ni][1] = *(const bf16x8*)(lds + 16384 + boff + (2 + ni) * 1024 + x1);
    }
    if (!last) { STA2(0, kt3, 1); STA2(1, kt3, 1); }
    BAR8(); WLG8();
    __builtin_amdgcn_s_setprio(1);
    MM2(2, 2, fAb, fBb, 0, 0); MM2(2, 3, fAb, fBb, 0, 1);
    MM2(3, 2, fAb, fBb, 1, 0); MM2(3, 3, fAb, fBb, 1, 1);
    __builtin_amdgcn_s_setprio(0);
    BAR8();

    if (!last) { STB2(0, kt3, 1); STB2(1, kt3, 1); }
    BAR8(); WLG8();
    __builtin_amdgcn_s_setprio(1);
    MM2(0, 2, fAa, fBb, 0, 0); MM2(0, 3, fAa, fBb, 0, 1);
    MM2(1, 2, fAa, fBb, 1, 0); MM2(1, 3, fAa, fBb, 1, 1);
    __builtin_amdgcn_s_setprio(0);
    if (last) { WVM8(0); } else { WVM8(6); }     // c2 fully landed past here
    BAR8();
  }

  // ---- epilogue: fp32 C write --------------------------------------------
  const int crow = m0 + wm * 64 + quad * 4;
  const int ccol = n0 + wn * 64 + c;
#pragma unroll
  for (int mf = 0; mf < 4; ++mf)
#pragma unroll
    for (int nf = 0; nf < 4; ++nf)
#pragma unroll
      for (int r = 0; r < 4; ++r)
        C[(size_t)(crow + mf * 16 + r) * N + ccol + nf * 16] = acc[mf][nf][r];
#undef STA2
#undef STB2
#undef BAR8
#undef WLG8
#undef WVM8
#undef MM2
}

// ------ flash attention, causal, GQA; fixed-max softmax (RMSNorm bound) -----
// v6 = v4's verified body (32 q-rows/wave, DMA-dbuf K/V staged under compute,
// swizzled P, mask kt>=2t) with the strip PAIRING removed: one 128-row strip
// per block, grid (16,16,2)=512 blocks. v5 showed grid=256 (1 blk/CU) was the
// occupancy binder; v5's reg-prefetch fix put LDS fill on the critical path
// (68->90us). v6 keeps v4's async staging AND doubles the grid. LDS 81920B
// (2x = exactly 160KB/CU -> 2 blocks/CU if granted as declared, like v3/v5).
__global__ __launch_bounds__(256) void attn_fwd(const u16* __restrict__ qb,
                                                const u16* __restrict__ kb,
                                                const u16* __restrict__ vt,
                                                u16* __restrict__ ob) {
  __shared__ __align__(16) u16 lds[32768 + 8192];  // K dbuf 32K, V dbuf 32K, P 16K
  // K[bs] @ bs*8192 ; V[bs] @ 16384 + bs*8192 ; P @ 32768 (2048/wave)
  const int t = 15 - blockIdx.x;            // long strips dispatch first
  const int h = blockIdx.y, b = blockIdx.z;
  const int hk = h >> 2;
  const int tid = threadIdx.x, wave = tid >> 6, lane = tid & 63;
  const int c = lane & 15, quad = lane >> 4;
  const int lr = lane >> 2, lp = lane & 3;
  const int lpg = (lp + 4 - ((lr >> 1) & 3)) & 3;
  const int swq = ((quad + (c >> 1)) & 3) * 8;
  const int psw = (c & 7) << 3;            // P granule swizzle (u16 units)
  const u16* qg = qb + ((size_t)b * HQ_ + h) * (size_t)Q_ * D_;
  const u16* kg = kb + ((size_t)b * HKV_ + hk) * (size_t)Q_ * D_;
  const u16* vg = vt + ((size_t)b * HKV_ + hk) * (size_t)D_ * Q_;
  u16* Pw = lds + 32768 + wave * 2048;     // 32 rows x 64 u16, swizzled
  u16* Bw = lds + wave * 2176;             // epilogue bounce (K region, dead)

#define ASTAGE(KT, BS)                                                        \
  { _Pragma("unroll")                                                         \
    for (int i = 0; i < 4; i++) {                                             \
      gl2lds16(lds + (BS) * 8192 + (size_t)(i * 256 + wave * 64) * 8,         \
               kg + ((size_t)(KT) * 64 + wave * 16 + lr) * D_ + i * 32 + lpg * 8); \
      int d = (i & 1) * 64 + wave * 16 + lr;                                  \
      gl2lds16(lds + 16384 + (BS) * 8192 + (size_t)(i * 256 + wave * 64) * 8, \
               vg + (size_t)d * Q_ + (KT) * 64 + (i >> 1) * 32 + lpg * 8);    \
    } }
#define MFMA_A(A0, B0, C0) __builtin_amdgcn_mfma_f32_16x16x32_bf16(A0, B0, C0, 0, 0, 0)

  const int q0 = t * 128;
  const int qbase = q0 + wave * 32;
  bf16x8 qf[2][4];
#pragma unroll
  for (int qh = 0; qh < 2; qh++)
#pragma unroll
    for (int kk = 0; kk < 4; kk++)
      qf[qh][kk] = *(const bf16x8*)(qg + (size_t)(qbase + qh * 16 + c) * D_ +
                                    kk * 32 + quad * 8);
  f32x4 Oa[8][2] = {};
  float l0 = 0.f, l1 = 0.f;

  ASTAGE(0, 0);

  const int nkt = 2 * t + 2;
#pragma unroll 1
  for (int kt = 0; kt < nkt; kt++) {
    const int bs = kt & 1;
    __syncthreads();             // DMA(kt) landed + all waves joined
    if (kt < nkt - 1) ASTAGE(kt + 1, bs ^ 1);
    const u16* Ksb = lds + bs * 8192;
    const u16* Vsb = lds + 16384 + bs * 8192;
    f32x4 S[4][2];
#pragma unroll
    for (int n = 0; n < 4; n++) {
      S[n][0] = f32x4{-FMAX_, -FMAX_, -FMAX_, -FMAX_};
      S[n][1] = f32x4{-FMAX_, -FMAX_, -FMAX_, -FMAX_};
#pragma unroll
      for (int kk = 0; kk < 4; kk++) {
        bf16x8 kf = *(const bf16x8*)(Ksb + kk * 2048 + (n * 16 + c) * 32 + swq);
        S[n][0] = MFMA_A(kf, qf[0][kk], S[n][0]);
        S[n][1] = MFMA_A(kf, qf[1][kk], S[n][1]);
      }
    }
    if (kt >= 2 * t) {           // possibly-masked tiles
#pragma unroll
      for (int n = 0; n < 4; n++)
#pragma unroll
        for (int qh = 0; qh < 2; qh++)
#pragma unroll
          for (int r = 0; r < 4; r++) {
            int key = kt * 64 + n * 16 + quad * 4 + r;
            if (key > qbase + qh * 16 + c) S[n][qh][r] = -1e9f;  // exp2 -> 0
          }
    }
#pragma unroll
    for (int n = 0; n < 4; n++)
#pragma unroll
      for (int qh = 0; qh < 2; qh++) {
        float p0 = __builtin_amdgcn_exp2f(S[n][qh][0]);
        float p1 = __builtin_amdgcn_exp2f(S[n][qh][1]);
        float p2 = __builtin_amdgcn_exp2f(S[n][qh][2]);
        float p3 = __builtin_amdgcn_exp2f(S[n][qh][3]);
        if (qh) l1 += (p0 + p1) + (p2 + p3);
        else    l0 += (p0 + p1) + (p2 + p3);
        short4 pk;
        pk.x = (short)f2bf_t(p0); pk.y = (short)f2bf_t(p1);
        pk.z = (short)f2bf_t(p2); pk.w = (short)f2bf_t(p3);
        *(short4*)(Pw + (qh * 16 + c) * 64 + ((n * 16 + quad * 4) ^ psw)) = pk;
      }
    bf16x8 pf[2][2];
#pragma unroll
    for (int qh = 0; qh < 2; qh++)
#pragma unroll
      for (int kk2 = 0; kk2 < 2; kk2++)
        pf[qh][kk2] = *(const bf16x8*)(Pw + (qh * 16 + c) * 64 +
                                       ((kk2 * 32 + quad * 8) ^ psw));
#pragma unroll
    for (int md = 0; md < 8; md++)
#pragma unroll
      for (int kk2 = 0; kk2 < 2; kk2++) {
        bf16x8 vf = *(const bf16x8*)(Vsb + kk2 * 4096 + (md * 16 + c) * 32 + swq);
        Oa[md][0] = MFMA_A(vf, pf[0][kk2], Oa[md][0]);
        Oa[md][1] = MFMA_A(vf, pf[1][kk2], Oa[md][1]);
      }
  }
  // epilogue: reduce l, normalize, transpose via bounce, store (2 passes)
  l0 += __shfl_xor(l0, 16); l0 += __shfl_xor(l0, 32);
  l1 += __shfl_xor(l1, 16); l1 += __shfl_xor(l1, 32);
  __syncthreads();    // all waves done with K/V reads; K region = bounce
#pragma unroll
  for (int qh = 0; qh < 2; qh++) {
    const float invl = 1.f / (qh ? l1 : l0);
#pragma unroll
    for (int md = 0; md < 8; md++) {
      short4 ok;
      ok.x = (short)f2bf(Oa[md][qh][0] * invl);
      ok.y = (short)f2bf(Oa[md][qh][1] * invl);
      ok.z = (short)f2bf(Oa[md][qh][2] * invl);
      ok.w = (short)f2bf(Oa[md][qh][3] * invl);
      *(short4*)(Bw + c * 136 + md * 16 + quad * 4) = ok;
    }
    const int orow = q0 + wave * 32 + qh * 16 + lr;
#pragma unroll
    for (int tt = 0; tt < 4; tt++) {
      bf16x8 ov = *(const bf16x8*)(Bw + lr * 136 + lp * 32 + tt * 8);
      *(bf16x8*)(ob + ((size_t)(b * Q_ + orow) * HQ_ + h) * D_ + lp * 32 + tt * 8) = ov;
    }
    // WAR fence: pass-0 bounce reads must land before pass-1 overwrites
    asm volatile("s_waitcnt lgkmcnt(0)" ::: "memory");
    __builtin_amdgcn_sched_barrier(0);
  }
#undef ASTAGE
#undef MFMA_A
}

// ---------------- launcher ----------------
extern "C" void kernel_launch(void* const* d_in, const int* in_sizes, int n_in,
                              void* d_out, int out_size, void* d_ws, size_t ws_size,
                              hipStream_t stream) {
  const int*   positions = (const int*)  d_in[0];
  const float* hidden    = (const float*)d_in[1];
  const float* wqkv      = (const float*)d_in[4];
  const float* wo        = (const float*)d_in[5];
  const float* qnw       = (const float*)d_in[6];
  const float* knw       = (const float*)d_in[7];
  char* ws = (char*)d_ws;
  u16*   hid_bf  = (u16*)(ws);                     // 16,777,216
  u16*   wqkv_bf = (u16*)(ws + 16777216);          // 12,582,912
  u16*   wo_bf   = (u16*)(ws + 29360128);          //  8,388,608
  u16*   q_bf    = (u16*)(ws + 37748736);          // 16,777,216
  u16*   k_bf    = (u16*)(ws + 54525952);          //  4,194,304
  u16*   vt_bf   = (u16*)(ws + 58720256);          //  4,194,304
  float* rope    = (float*)(ws + 62914560);        //  2,097,152
  u16*   attn_bf = hid_bf;                         // alias: dead after gemm_qkv8

  cvt_all<<<19456, 256, 0, stream>>>(hidden, wqkv, wo, positions,
                                     hid_bf, wqkv_bf, wo_bf, rope);
  gemm_qkv8<<<dim3(16, 12), 512, 0, stream>>>(hid_bf, wqkv_bf, rope, qnw, knw,
                                              q_bf, k_bf, vt_bf);
  attn_fwd<<<dim3(16, 16, 2), 256, 0, stream>>>(q_bf, k_bf, vt_bf, attn_bf);
  gemm_bt8<<<dim3(32, 8), 512, 0, stream>>>(attn_bf, wo_bf, (float*)d_out,
                                            4096, 2048, 2048);
}

// Round 11
// 279.099 us; speedup vs baseline: 1.0984x; 1.0882x over previous
//
#include <hip/hip_runtime.h>

// ---------------- problem constants ----------------
#define B_    2
#define Q_    2048
#define HID_  2048
#define HQ_   16
#define HKV_  4
#define D_    128
// softmax scale folded into q, in exp2 domain: D^-0.5 * log2(e)
#define QSC_  (0.08838834764831843f * 1.4426950408889634f)
#define LOG2_THETA 19.931568569324174f // log2(1e6)
// fixed softmax max: |score*log2e| <= sqrt(128)*1.4427 = 16.33 < 20 (RMSNorm'd q,k)
#define FMAX_ 20.0f

typedef unsigned short u16;
typedef __attribute__((ext_vector_type(8))) short bf16x8;
typedef __attribute__((ext_vector_type(4))) float f32x4;

__device__ __forceinline__ u16 f2bf(float x) {           // round-nearest-even
  union { float f; unsigned int u; } v; v.f = x;
  unsigned int r = v.u + 0x7FFFu + ((v.u >> 16) & 1u);
  return (u16)(r >> 16);
}
__device__ __forceinline__ u16 f2bf_t(float x) {         // truncate (hot loop)
  union { float f; unsigned int u; } v; v.f = x;
  return (u16)(v.u >> 16);
}

// async global->LDS, 16B per lane; lds must be the wave-uniform base
__device__ __forceinline__ void gl2lds16(u16* lds, const u16* g) {
  __builtin_amdgcn_global_load_lds((const __attribute__((address_space(1))) void*)g,
                                   (__attribute__((address_space(3))) void*)lds,
                                   16, 0, 0);
}

// ------- fused fp32->bf16 casts (hidden, wqkv, wo) + RoPE cos/sin table -----
#define N4_HID  2097152
#define N4_WQKV 1572864
#define N4_WO   1048576
#define N4_ALL  (N4_HID + N4_WQKV + N4_WO)     // 4718592 = 18432*256
#define NROPE   (B_ * Q_ * 64)                 // 262144  = 1024*256
__global__ __launch_bounds__(256) void cvt_all(const float* __restrict__ h,
                                               const float* __restrict__ wq,
                                               const float* __restrict__ wo,
                                               const int* __restrict__ pos,
                                               u16* __restrict__ oh,
                                               u16* __restrict__ owq,
                                               u16* __restrict__ owo,
                                               float* __restrict__ rope) {
  int i = blockIdx.x * 256 + threadIdx.x;
  if (i >= N4_ALL) {                            // RoPE table part
    int j = i - N4_ALL;                         // < NROPE
    int d = j & 63, row = j >> 6;
    float p = (float)pos[row];
    float inv = exp2f(-(float)d * (LOG2_THETA / 64.f));
    float sn, cn;
    sincosf(p * inv, &sn, &cn);
    ((float2*)rope)[j] = make_float2(cn, sn);
    return;
  }
  const float* src; u16* dst; int off;
  if (i < N4_HID)                 { src = h;  dst = oh;  off = i; }
  else if (i < N4_HID + N4_WQKV)  { src = wq; dst = owq; off = i - N4_HID; }
  else                            { src = wo; dst = owo; off = i - N4_HID - N4_WQKV; }
  float4 v = *(const float4*)(src + (size_t)off * 4);
  ushort4 o;
  o.x = f2bf(v.x); o.y = f2bf(v.y); o.z = f2bf(v.z); o.w = f2bf(v.w);
  *(ushort4*)(dst + (size_t)off * 4) = o;
}

// ------- fused QKV GEMM (256x256 8-phase) + RMSNorm + RoPE + layout ---------
// (unchanged from round 3 -- verified, bank-conflict-free)
__global__ __launch_bounds__(512) void gemm_qkv8(const u16* __restrict__ A,
                                                 const u16* __restrict__ Bw,
                                                 const float* __restrict__ rope,
                                                 const float* __restrict__ qw,
                                                 const float* __restrict__ kw,
                                                 u16* __restrict__ qb,
                                                 u16* __restrict__ kb,
                                                 u16* __restrict__ vt) {
  __shared__ __align__(16) u16 lds[65536];
  const int tid = threadIdx.x;
  const int wv = tid >> 6, lane = tid & 63;
  const int wm = wv >> 1, wn = wv & 1;             // 4M x 2N
  const int c = lane & 15, quad = lane >> 4;
  const int m0 = blockIdx.x * 256;
  const int by = blockIdx.y;
  const int n0 = by * 256;
  const int xg = ((lane & 7) ^ (lane >> 3)) * 8;   // staging source swizzle
  const int x0 = ((quad)     ^ (c & 7)) * 8;       // read swizzle, ks=0
  const int x1 = ((quad | 4) ^ (c & 7)) * 8;       // read swizzle, ks=1
  const int aoff = (wm >> 1) * 8192 + (wm & 1) * 4096 + c * 64;
  const int boff = 32768 + wn * 8192 + c * 64;
  const u16* Ag = A  + (size_t)m0 * HID_;
  const u16* Bg = Bw + (size_t)n0 * HID_;
  const int NIT = HID_ >> 7;                       // 16

#define STGQ(base, g, h, kt, buf)                                             \
  { _Pragma("unroll")                                                         \
    for (int j = 0; j < 2; ++j) {                                             \
      const int s = j * 8 + wv;                                               \
      gl2lds16(lds + (base) + (buf) * 16384 + (h) * 8192 + s * 512,           \
               (g) + (size_t)((h) * 128 + s * 8 + (lane >> 3)) * HID_         \
                   + (kt) * 64 + xg);                                         \
    } }
#define STGQ_A(h, kt, buf) STGQ(0,     Ag, h, kt, buf)
#define STGQ_B(h, kt, buf) STGQ(32768, Bg, h, kt, buf)
#define BARQ()  asm volatile("s_barrier" ::: "memory")
#define WLGQ()  { asm volatile("s_waitcnt lgkmcnt(0)" ::: "memory");          \
                  __builtin_amdgcn_sched_barrier(0); }
#define WVMQ(n) { asm volatile("s_waitcnt vmcnt(" #n ")" ::: "memory");       \
                  __builtin_amdgcn_sched_barrier(0); }
#define MMQ(MF, NF, FA, MI) {                                                 \
  acc[MF][NF] = __builtin_amdgcn_mfma_f32_16x16x32_bf16(FA[MI][0], fB[(NF)&3][0], \
                                                        acc[MF][NF], 0, 0, 0);\
  acc[MF][NF] = __builtin_amdgcn_mfma_f32_16x16x32_bf16(FA[MI][1], fB[(NF)&3][1], \
                                                        acc[MF][NF], 0, 0, 0); }

  f32x4 acc[4][8] = {};
  bf16x8 fAa[2][2], fAb[2][2], fB[4][2];

  STGQ_A(0, 0, 0); STGQ_A(1, 0, 0); STGQ_B(0, 0, 0); STGQ_B(1, 0, 0);
  STGQ_A(0, 1, 1); STGQ_B(0, 1, 1);
  WVMQ(4);
  BARQ();

#pragma unroll 1
  for (int it = 0; it < NIT; ++it) {
    const bool last = (it == NIT - 1);
    const int kt1 = 2 * it + 1, kt2 = 2 * it + 2, kt3 = 2 * it + 3;

#pragma unroll
    for (int mi = 0; mi < 2; ++mi) {
      fAa[mi][0] = *(const bf16x8*)(lds + aoff + mi * 1024 + x0);
      fAa[mi][1] = *(const bf16x8*)(lds + aoff + mi * 1024 + x1);
    }
#pragma unroll
    for (int nf = 0; nf < 4; ++nf) {
      fB[nf][0] = *(const bf16x8*)(lds + boff + nf * 1024 + x0);
      fB[nf][1] = *(const bf16x8*)(lds + boff + nf * 1024 + x1);
    }
    STGQ_A(1, kt1, 1);
    BARQ(); WLGQ();
    __builtin_amdgcn_s_setprio(1);
#pragma unroll
    for (int mi = 0; mi < 2; ++mi)
#pragma unroll
      for (int nf = 0; nf < 4; ++nf) MMQ(mi, nf, fAa, mi);
    __builtin_amdgcn_s_setprio(0);
    BARQ();

#pragma unroll
    for (int mi = 0; mi < 2; ++mi) {
      fAb[mi][0] = *(const bf16x8*)(lds + aoff + (2 + mi) * 1024 + x0);
      fAb[mi][1] = *(const bf16x8*)(lds + aoff + (2 + mi) * 1024 + x1);
    }
    STGQ_B(1, kt1, 1);
    BARQ(); WLGQ();
    __builtin_amdgcn_s_setprio(1);
#pragma unroll
    for (int mi = 0; mi < 2; ++mi)
#pragma unroll
      for (int nf = 0; nf < 4; ++nf) MMQ(2 + mi, nf, fAb, mi);
    __builtin_amdgcn_s_setprio(0);
    BARQ();

#pragma unroll
    for (int nf = 0; nf < 4; ++nf) {
      fB[nf][0] = *(const bf16x8*)(lds + boff + (4 + nf) * 1024 + x0);
      fB[nf][1] = *(const bf16x8*)(lds + boff + (4 + nf) * 1024 + x1);
    }
    if (!last) STGQ_A(0, kt2, 0);
    BARQ(); WLGQ();
    __builtin_amdgcn_s_setprio(1);
#pragma unroll
    for (int mi = 0; mi < 2; ++mi)
#pragma unroll
      for (int nf = 4; nf < 8; ++nf) MMQ(2 + mi, nf, fAb, mi);
    __builtin_amdgcn_s_setprio(0);
    BARQ();

    if (!last) STGQ_B(0, kt2, 0);
    BARQ(); WLGQ();
    __builtin_amdgcn_s_setprio(1);
#pragma unroll
    for (int mi = 0; mi < 2; ++mi)
#pragma unroll
      for (int nf = 4; nf < 8; ++nf) MMQ(mi, nf, fAa, mi);
    __builtin_amdgcn_s_setprio(0);
    if (last) { WVMQ(0); } else { WVMQ(4); }
    BARQ();

#pragma unroll
    for (int mi = 0; mi < 2; ++mi) {
      fAa[mi][0] = *(const bf16x8*)(lds + 16384 + aoff + mi * 1024 + x0);
      fAa[mi][1] = *(const bf16x8*)(lds + 16384 + aoff + mi * 1024 + x1);
    }
#pragma unroll
    for (int nf = 0; nf < 4; ++nf) {
      fB[nf][0] = *(const bf16x8*)(lds + 16384 + boff + nf * 1024 + x0);
      fB[nf][1] = *(const bf16x8*)(lds + 16384 + boff + nf * 1024 + x1);
    }
    if (!last) STGQ_A(1, kt2, 0);
    BARQ(); WLGQ();
    __builtin_amdgcn_s_setprio(1);
#pragma unroll
    for (int mi = 0; mi < 2; ++mi)
#pragma unroll
      for (int nf = 0; nf < 4; ++nf) MMQ(mi, nf, fAa, mi);
    __builtin_amdgcn_s_setprio(0);
    BARQ();

#pragma unroll
    for (int mi = 0; mi < 2; ++mi) {
      fAb[mi][0] = *(const bf16x8*)(lds + 16384 + aoff + (2 + mi) * 1024 + x0);
      fAb[mi][1] = *(const bf16x8*)(lds + 16384 + aoff + (2 + mi) * 1024 + x1);
    }
    if (!last) STGQ_B(1, kt2, 0);
    BARQ(); WLGQ();
    __builtin_amdgcn_s_setprio(1);
#pragma unroll
    for (int mi = 0; mi < 2; ++mi)
#pragma unroll
      for (int nf = 0; nf < 4; ++nf) MMQ(2 + mi, nf, fAb, mi);
    __builtin_amdgcn_s_setprio(0);
    BARQ();

#pragma unroll
    for (int nf = 0; nf < 4; ++nf) {
      fB[nf][0] = *(const bf16x8*)(lds + 16384 + boff + (4 + nf) * 1024 + x0);
      fB[nf][1] = *(const bf16x8*)(lds + 16384 + boff + (4 + nf) * 1024 + x1);
    }
    if (!last) STGQ_A(0, kt3, 1);
    BARQ(); WLGQ();
    __builtin_amdgcn_s_setprio(1);
#pragma unroll
    for (int mi = 0; mi < 2; ++mi)
#pragma unroll
      for (int nf = 4; nf < 8; ++nf) MMQ(2 + mi, nf, fAb, mi);
    __builtin_amdgcn_s_setprio(0);
    BARQ();

    if (!last) STGQ_B(0, kt3, 1);
    BARQ(); WLGQ();
    __builtin_amdgcn_s_setprio(1);
#pragma unroll
    for (int mi = 0; mi < 2; ++mi)
#pragma unroll
      for (int nf = 4; nf < 8; ++nf) MMQ(mi, nf, fAa, mi);
    __builtin_amdgcn_s_setprio(0);
    if (last) { WVMQ(0); } else { WVMQ(4); }
    BARQ();
  }

  const int h = by * 2 + wn;
  if (h < 20) {
    const bool isq = h < 16;
    const float* w = isq ? qw : kw;
    const float osc = isq ? QSC_ : 1.f;
    float wl[8];
#pragma unroll
    for (int nf = 0; nf < 8; ++nf) wl[nf] = w[nf * 16 + c];
    u16* dstbuf = isq ? qb : kb;
    const int hbase = isq ? h : (h - 16);
    const int nheads = isq ? HQ_ : HKV_;
    u16* lw = lds + wv * 4224;                   // 32 rows x stride 132
#pragma unroll
    for (int pass = 0; pass < 2; ++pass) {
#pragma unroll
      for (int mi = 0; mi < 2; ++mi) {
        const int mf = pass * 2 + mi;
#pragma unroll
        for (int r = 0; r < 4; ++r) {
          const int row = m0 + wm * 64 + mf * 16 + quad * 4 + r;
          const int q = row & (Q_ - 1), b = row >> 11;
          float ss = 0.f;
#pragma unroll
          for (int nf = 0; nf < 8; ++nf) ss += acc[mf][nf][r] * acc[mf][nf][r];
          ss += __shfl_xor(ss, 1); ss += __shfl_xor(ss, 2);
          ss += __shfl_xor(ss, 4); ss += __shfl_xor(ss, 8);
          const float rn = rsqrtf(ss * (1.f / 128.f) + 1e-6f) * osc;
          u16* lrow = lw + (mi * 16 + quad * 4 + r) * 132;
#pragma unroll
          for (int ni = 0; ni < 4; ni++) {
            float2 cssn = *(const float2*)(rope +
                ((size_t)(b * Q_ + q) * 64 + ni * 16 + c) * 2);
            float x1 = acc[mf][ni][r]     * wl[ni]     * rn;
            float x2 = acc[mf][ni + 4][r] * wl[ni + 4] * rn;
            lrow[ni * 16 + c]       = f2bf(x1 * cssn.x - x2 * cssn.y);
            lrow[(ni + 4) * 16 + c] = f2bf(x2 * cssn.x + x1 * cssn.y);
          }
        }
      }
#pragma unroll
      for (int itr = 0; itr < 8; ++itr) {
        const int rl = itr * 4 + quad;           // 0..31
        const int rowg = m0 + wm * 64 + pass * 32 + rl;
        const int q = rowg & (Q_ - 1), b = rowg >> 11;
        u16* dst = dstbuf + (((size_t)(b * nheads) + hbase) * Q_ + q) * D_ + c * 8;
        *(bf16x8*)dst = *(const bf16x8*)(lw + rl * 132 + c * 8);
      }
    }
  } else {
    const int hk = h - 20;
    const int bb = m0 >> 11;
    const int q0w = (m0 & (Q_ - 1)) + wm * 64;
    u16* lw = lds + wv * 4352;                   // 64 d-rows x stride 68
#pragma unroll
    for (int pass = 0; pass < 2; ++pass) {
#pragma unroll
      for (int nfl = 0; nfl < 4; ++nfl) {
        const int nf = pass * 4 + nfl;
#pragma unroll
        for (int mf = 0; mf < 4; ++mf) {
          short4 pv;
          pv.x = (short)f2bf(acc[mf][nf][0]); pv.y = (short)f2bf(acc[mf][nf][1]);
          pv.z = (short)f2bf(acc[mf][nf][2]); pv.w = (short)f2bf(acc[mf][nf][3]);
          *(short4*)(lw + (nfl * 16 + c) * 68 + mf * 16 + quad * 4) = pv;
        }
      }
#pragma unroll
      for (int itr = 0; itr < 8; ++itr) {
        const int dl = itr * 8 + (lane >> 3);    // 0..63
        const int d = pass * 64 + dl;
        u16* dst = vt + (((size_t)(bb * HKV_) + hk) * D_ + d) * Q_ +
                   q0w + (lane & 7) * 8;
        *(bf16x8*)dst = *(const bf16x8*)(lw + dl * 68 + (lane & 7) * 8);
      }
    }
  }
#undef STGQ
#undef STGQ_A
#undef STGQ_B
#undef BARQ
#undef WLGQ
#undef WVMQ
#undef MMQ
}

// ------------- bf16 GEMM, 128x256 tile, 8-phase counted-vmcnt schedule ------
// (unchanged from round 5 -- verified; grid 256 = 100% CU fill)
__global__ __launch_bounds__(512) void gemm_bt8(const u16* __restrict__ A,
                                                const u16* __restrict__ Bw,
                                                float* __restrict__ C,
                                                int M, int N, int K) {
  __shared__ __align__(16) u16 lds[49152];
  const int tid = threadIdx.x;
  const int wv = tid >> 6, lane = tid & 63;
  const int wm = wv >> 2, wn = wv & 3;             // 2M x 4N
  const int c = lane & 15, quad = lane >> 4;
  const int m0 = blockIdx.x * 128, n0 = blockIdx.y * 256;
  const int xg = ((lane & 7) ^ (lane >> 3)) * 8;   // staging source swizzle
  const int x0 = ((quad)     ^ (c & 7)) * 8;       // read swizzle, ks=0
  const int x1 = ((quad | 4) ^ (c & 7)) * 8;       // read swizzle, ks=1
  const int aoff = wm * 4096 + c * 64;                                  // +buf*8192
  const int boff = 16384 + (wn >> 1) * 8192 + (wn & 1) * 4096 + c * 64; // +buf*16384
  const u16* Ag = A  + (size_t)m0 * K;
  const u16* Bg = Bw + (size_t)n0 * K;
  const int NIT = K >> 7;                          // 16

#define STA2(h, kt, buf)                                                      \
  gl2lds16(lds + (buf) * 8192 + (h) * 4096 + wv * 512,                        \
           Ag + (size_t)((h) * 64 + wv * 8 + (lane >> 3)) * K + (kt) * 64 + xg);
#define STB2(h, kt, buf)                                                      \
  { _Pragma("unroll")                                                         \
    for (int j = 0; j < 2; ++j)                                               \
      gl2lds16(lds + 16384 + (buf) * 16384 + (h) * 8192 + j * 4096 + wv * 512,\
               Bg + (size_t)((h) * 128 + j * 64 + wv * 8 + (lane >> 3)) * K   \
                   + (kt) * 64 + xg); }
#define BAR8()  asm volatile("s_barrier" ::: "memory")
#define WLG8()  { asm volatile("s_waitcnt lgkmcnt(0)" ::: "memory");          \
                  __builtin_amdgcn_sched_barrier(0); }
#define WVM8(n) { asm volatile("s_waitcnt vmcnt(" #n ")" ::: "memory");       \
                  __builtin_amdgcn_sched_barrier(0); }
#define MM2(MF, NF, FA, FB, MI, NI) {                                         \
  acc[MF][NF] = __builtin_amdgcn_mfma_f32_16x16x32_bf16(FA[MI][0], FB[NI][0], \
                                                        acc[MF][NF], 0, 0, 0);\
  acc[MF][NF] = __builtin_amdgcn_mfma_f32_16x16x32_bf16(FA[MI][1], FB[NI][1], \
                                                        acc[MF][NF], 0, 0, 0); }

  f32x4 acc[4][4] = {};
  bf16x8 fAa[2][2], fAb[2][2], fBa[2][2], fBb[2][2];

  // prologue: c0 -> buf0 (6 loads), c1 -> buf1 (6); wait c0, leave c1 flying
  STA2(0, 0, 0); STA2(1, 0, 0); STB2(0, 0, 0); STB2(1, 0, 0);
  STA2(0, 1, 1); STA2(1, 1, 1); STB2(0, 1, 1); STB2(1, 1, 1);
  WVM8(6);
  BAR8();

#pragma unroll 1
  for (int it = 0; it < NIT; ++it) {
    const bool last = (it == NIT - 1);
    const int kt2 = 2 * it + 2, kt3 = 2 * it + 3;

    // ================= first half: compute K-tile 2it from buf0 ===========
#pragma unroll
    for (int mi = 0; mi < 2; ++mi) {
      fAa[mi][0] = *(const bf16x8*)(lds + aoff + mi * 1024 + x0);
      fAa[mi][1] = *(const bf16x8*)(lds + aoff + mi * 1024 + x1);
      fBa[mi][0] = *(const bf16x8*)(lds + boff + mi * 1024 + x0);
      fBa[mi][1] = *(const bf16x8*)(lds + boff + mi * 1024 + x1);
    }
    BAR8(); WLG8();
    __builtin_amdgcn_s_setprio(1);
    MM2(0, 0, fAa, fBa, 0, 0); MM2(0, 1, fAa, fBa, 0, 1);
    MM2(1, 0, fAa, fBa, 1, 0); MM2(1, 1, fAa, fBa, 1, 1);
    __builtin_amdgcn_s_setprio(0);
    BAR8();

#pragma unroll
    for (int mi = 0; mi < 2; ++mi) {
      fAb[mi][0] = *(const bf16x8*)(lds + aoff + (2 + mi) * 1024 + x0);
      fAb[mi][1] = *(const bf16x8*)(lds + aoff + (2 + mi) * 1024 + x1);
    }
    BAR8(); WLG8();
    __builtin_amdgcn_s_setprio(1);
    MM2(2, 0, fAb, fBa, 0, 0); MM2(2, 1, fAb, fBa, 0, 1);
    MM2(3, 0, fAb, fBa, 1, 0); MM2(3, 1, fAb, fBa, 1, 1);
    __builtin_amdgcn_s_setprio(0);
    BAR8();

#pragma unroll
    for (int ni = 0; ni < 2; ++ni) {
      fBb[ni][0] = *(const bf16x8*)(lds + boff + (2 + ni) * 1024 + x0);
      fBb[ni][1] = *(const bf16x8*)(lds + boff + (2 + ni) * 1024 + x1);
    }
    if (!last) { STA2(0, kt2, 0); STA2(1, kt2, 0); }
    BAR8(); WLG8();
    __builtin_amdgcn_s_setprio(1);
    MM2(2, 2, fAb, fBb, 0, 0); MM2(2, 3, fAb, fBb, 0, 1);
    MM2(3, 2, fAb, fBb, 1, 0); MM2(3, 3, fAb, fBb, 1, 1);
    __builtin_amdgcn_s_setprio(0);
    BAR8();

    if (!last) { STB2(0, kt2, 0); STB2(1, kt2, 0); }
    BAR8(); WLG8();
    __builtin_amdgcn_s_setprio(1);
    MM2(0, 2, fAa, fBb, 0, 0); MM2(0, 3, fAa, fBb, 0, 1);
    MM2(1, 2, fAa, fBb, 1, 0); MM2(1, 3, fAa, fBb, 1, 1);
    __builtin_amdgcn_s_setprio(0);
    if (last) { WVM8(0); } else { WVM8(6); }     // c1 fully landed past here
    BAR8();

    // ================= second half: compute K-tile 2it+1 from buf1 =========
#pragma unroll
    for (int mi = 0; mi < 2; ++mi) {
      fAa[mi][0] = *(const bf16x8*)(lds + 8192 + aoff + mi * 1024 + x0);
      fAa[mi][1] = *(const bf16x8*)(lds + 8192 + aoff + mi * 1024 + x1);
      fBa[mi][0] = *(const bf16x8*)(lds + 16384 + boff + mi * 1024 + x0);
      fBa[mi][1] = *(const bf16x8*)(lds + 16384 + boff + mi * 1024 + x1);
    }
    BAR8(); WLG8();
    __builtin_amdgcn_s_setprio(1);
    MM2(0, 0, fAa, fBa, 0, 0); MM2(0, 1, fAa, fBa, 0, 1);
    MM2(1, 0, fAa, fBa, 1, 0); MM2(1, 1, fAa, fBa, 1, 1);
    __builtin_amdgcn_s_setprio(0);
    BAR8();

#pragma unroll
    for (int mi = 0; mi < 2; ++mi) {
      fAb[mi][0] = *(const bf16x8*)(lds + 8192 + aoff + (2 + mi) * 1024 + x0);
      fAb[mi][1] = *(const bf16x8*)(lds + 8192 + aoff + (2 + mi) * 1024 + x1);
    }
    BAR8(); WLG8();
    __builtin_amdgcn_s_setprio(1);
    MM2(2, 0, fAb, fBa, 0, 0); MM2(2, 1, fAb, fBa, 0, 1);
    MM2(3, 0, fAb, fBa, 1, 0); MM2(3, 1, fAb, fBa, 1, 1);
    __builtin_amdgcn_s_setprio(0);
    BAR8();

#pragma unroll
    for (int ni = 0; ni < 2; ++ni) {
      fBb[ni][0] = *(const bf16x8*)(lds + 16384 + boff + (2 + ni) * 1024 + x0);
      fBb[ni][1] = *(const bf16x8*)(lds + 16384 + boff + (2 + ni) * 1024 + x1);
    }
    if (!last) { STA2(0, kt3, 1); STA2(1, kt3, 1); }
    BAR8(); WLG8();
    __builtin_amdgcn_s_setprio(1);
    MM2(2, 2, fAb, fBb, 0, 0); MM2(2, 3, fAb, fBb, 0, 1);
    MM2(3, 2, fAb, fBb, 1, 0); MM2(3, 3, fAb, fBb, 1, 1);
    __builtin_amdgcn_s_setprio(0);
    BAR8();

    if (!last) { STB2(0, kt3, 1); STB2(1, kt3, 1); }
    BAR8(); WLG8();
    __builtin_amdgcn_s_setprio(1);
    MM2(0, 2, fAa, fBb, 0, 0); MM2(0, 3, fAa, fBb, 0, 1);
    MM2(1, 2, fAa, fBb, 1, 0); MM2(1, 3, fAa, fBb, 1, 1);
    __builtin_amdgcn_s_setprio(0);
    if (last) { WVM8(0); } else { WVM8(6); }     // c2 fully landed past here
    BAR8();
  }

  // ---- epilogue: fp32 C write --------------------------------------------
  const int crow = m0 + wm * 64 + quad * 4;
  const int ccol = n0 + wn * 64 + c;
#pragma unroll
  for (int mf = 0; mf < 4; ++mf)
#pragma unroll
    for (int nf = 0; nf < 4; ++nf)
#pragma unroll
      for (int r = 0; r < 4; ++r)
        C[(size_t)(crow + mf * 16 + r) * N + ccol + nf * 16] = acc[mf][nf][r];
#undef STA2
#undef STB2
#undef BAR8
#undef WLG8
#undef WVM8
#undef MM2
}

// ------ flash attention, causal, GQA; fixed-max softmax (RMSNorm bound) -----
// v7 = the round-5 v2 kernel restored verbatim (session-best total 281.5us:
// 16 q-rows/wave, K/V DMA double-buffer staged under compute, paired 64-row
// strips (t, 31-t) -> uniform 33 k-tile iterations, 73KB LDS, grid 512),
// plus T5 s_setprio(1/0) around the QK and PV MFMA clusters (m191: +4-7% on
// attn with multiple independent blocks/CU at different phases). The v3-v6
// qh/occupancy arc never beat v2 (occupancy counter flat vs LDS = unreliable).
__global__ __launch_bounds__(256) void attn_fwd(const u16* __restrict__ qb,
                                                const u16* __restrict__ kb,
                                                const u16* __restrict__ vt,
                                                u16* __restrict__ ob) {
  __shared__ __align__(16) u16 lds[2 * 8192 + 2 * 8192 + 4608];  // 73 KB
  // K[b] @ b*8192 ; V[b] @ 16384 + b*8192 ; P @ 32768 ; bounce reuses K0/K1
  const int p = blockIdx.x, h = blockIdx.y, b = blockIdx.z;
  const int hk = h >> 2;
  const int tid = threadIdx.x, wave = tid >> 6, lane = tid & 63;
  const int c = lane & 15, quad = lane >> 4;
  const int lr = lane >> 2, lp = lane & 3;
  const int lpg = (lp + 4 - ((lr >> 1) & 3)) & 3;
  const int swq = ((quad + (c >> 1)) & 3) * 8;
  const u16* qg = qb + ((size_t)b * HQ_ + h) * (size_t)Q_ * D_;
  const u16* kg = kb + ((size_t)b * HKV_ + hk) * (size_t)Q_ * D_;
  const u16* vg = vt + ((size_t)b * HKV_ + hk) * (size_t)D_ * Q_;
  u16* Pw = lds + 32768 + wave * 1152;
  u16* Bw = lds + wave * 2176;

#define ASTAGE(KT, BS)                                                        \
  { _Pragma("unroll")                                                         \
    for (int i = 0; i < 4; i++) {                                             \
      gl2lds16(lds + (BS) * 8192 + (size_t)(i * 256 + wave * 64) * 8,         \
               kg + ((size_t)(KT) * 64 + wave * 16 + lr) * D_ + i * 32 + lpg * 8); \
      int d = (i & 1) * 64 + wave * 16 + lr;                                  \
      gl2lds16(lds + 16384 + (BS) * 8192 + (size_t)(i * 256 + wave * 64) * 8, \
               vg + (size_t)d * Q_ + (KT) * 64 + (i >> 1) * 32 + lpg * 8);    \
    } }

#pragma unroll 1
  for (int tp = 0; tp < 2; tp++) {
    const int t = tp ? (31 - p) : p;
    const int q0 = t * 64;
    const int qrow = q0 + wave * 16 + c;
    bf16x8 qf[4];
#pragma unroll
    for (int kk = 0; kk < 4; kk++)
      qf[kk] = *(const bf16x8*)(qg + (size_t)qrow * D_ + kk * 32 + quad * 8);
    f32x4 Oa[8] = {};
    float l_acc = 0.f;

    if (tp) __syncthreads();       // strip-0 bounce reads done before refill
    ASTAGE(0, 0);

#pragma unroll 1
    for (int kt = 0; kt <= t; kt++) {
      const int bs = kt & 1;
      __syncthreads();             // DMA(kt) landed + all waves joined
      if (kt < t) ASTAGE(kt + 1, bs ^ 1);
      const u16* Ksb = lds + bs * 8192;
      const u16* Vsb = lds + 16384 + bs * 8192;
      f32x4 S[4];
      __builtin_amdgcn_s_setprio(1);
#pragma unroll
      for (int n = 0; n < 4; n++) {
        f32x4 a = {-FMAX_, -FMAX_, -FMAX_, -FMAX_};   // bias folded into C
#pragma unroll
        for (int kk = 0; kk < 4; kk++) {
          bf16x8 kf = *(const bf16x8*)(Ksb + kk * 2048 + (n * 16 + c) * 32 + swq);
          a = __builtin_amdgcn_mfma_f32_16x16x32_bf16(kf, qf[kk], a, 0, 0, 0);
        }
        S[n] = a;
      }
      __builtin_amdgcn_s_setprio(0);
      if (kt == t) {
#pragma unroll
        for (int n = 0; n < 4; n++)
#pragma unroll
          for (int r = 0; r < 4; r++) {
            int key = kt * 64 + n * 16 + quad * 4 + r;
            if (key > qrow) S[n][r] = -1e9f;          // exp2 -> 0
          }
      }
#pragma unroll
      for (int n = 0; n < 4; n++) {
        float p0 = __builtin_amdgcn_exp2f(S[n][0]);
        float p1 = __builtin_amdgcn_exp2f(S[n][1]);
        float p2 = __builtin_amdgcn_exp2f(S[n][2]);
        float p3 = __builtin_amdgcn_exp2f(S[n][3]);
        l_acc += (p0 + p1) + (p2 + p3);
        short4 pk;
        pk.x = (short)f2bf_t(p0); pk.y = (short)f2bf_t(p1);
        pk.z = (short)f2bf_t(p2); pk.w = (short)f2bf_t(p3);
        *(short4*)(Pw + c * 72 + n * 16 + quad * 4) = pk;
      }
      bf16x8 pf[2];
#pragma unroll
      for (int kk2 = 0; kk2 < 2; kk2++)
        pf[kk2] = *(const bf16x8*)(Pw + c * 72 + kk2 * 32 + quad * 8);
      __builtin_amdgcn_s_setprio(1);
#pragma unroll
      for (int md = 0; md < 8; md++)
#pragma unroll
        for (int kk2 = 0; kk2 < 2; kk2++) {
          bf16x8 vf = *(const bf16x8*)(Vsb + kk2 * 4096 + (md * 16 + c) * 32 + swq);
          Oa[md] = __builtin_amdgcn_mfma_f32_16x16x32_bf16(vf, pf[kk2], Oa[md], 0, 0, 0);
        }
      __builtin_amdgcn_s_setprio(0);
    }
    // strip epilogue: reduce l across quads, normalize, transpose, store
    float l_row = l_acc;
    l_row += __shfl_xor(l_row, 16);
    l_row += __shfl_xor(l_row, 32);
    __syncthreads();    // all waves done with K/V reads; K region = bounce
    const float invl = 1.f / l_row;
#pragma unroll
    for (int md = 0; md < 8; md++) {
      short4 ok;
      ok.x = (short)f2bf(Oa[md][0] * invl); ok.y = (short)f2bf(Oa[md][1] * invl);
      ok.z = (short)f2bf(Oa[md][2] * invl); ok.w = (short)f2bf(Oa[md][3] * invl);
      *(short4*)(Bw + c * 136 + md * 16 + quad * 4) = ok;
    }
    const int orow = q0 + wave * 16 + lr;
#pragma unroll
    for (int tt = 0; tt < 4; tt++) {
      bf16x8 ov = *(const bf16x8*)(Bw + lr * 136 + lp * 32 + tt * 8);
      *(bf16x8*)(ob + ((size_t)(b * Q_ + orow) * HQ_ + h) * D_ + lp * 32 + tt * 8) = ov;
    }
  }
#undef ASTAGE
}

// ---------------- launcher ----------------
extern "C" void kernel_launch(void* const* d_in, const int* in_sizes, int n_in,
                              void* d_out, int out_size, void* d_ws, size_t ws_size,
                              hipStream_t stream) {
  const int*   positions = (const int*)  d_in[0];
  const float* hidden    = (const float*)d_in[1];
  const float* wqkv      = (const float*)d_in[4];
  const float* wo        = (const float*)d_in[5];
  const float* qnw       = (const float*)d_in[6];
  const float* knw       = (const float*)d_in[7];
  char* ws = (char*)d_ws;
  u16*   hid_bf  = (u16*)(ws);                     // 16,777,216
  u16*   wqkv_bf = (u16*)(ws + 16777216);          // 12,582,912
  u16*   wo_bf   = (u16*)(ws + 29360128);          //  8,388,608
  u16*   q_bf    = (u16*)(ws + 37748736);          // 16,777,216
  u16*   k_bf    = (u16*)(ws + 54525952);          //  4,194,304
  u16*   vt_bf   = (u16*)(ws + 58720256);          //  4,194,304
  float* rope    = (float*)(ws + 62914560);        //  2,097,152
  u16*   attn_bf = hid_bf;                         // alias: dead after gemm_qkv8

  cvt_all<<<19456, 256, 0, stream>>>(hidden, wqkv, wo, positions,
                                     hid_bf, wqkv_bf, wo_bf, rope);
  gemm_qkv8<<<dim3(16, 12), 512, 0, stream>>>(hid_bf, wqkv_bf, rope, qnw, knw,
                                              q_bf, k_bf, vt_bf);
  attn_fwd<<<dim3(16, 16, 2), 256, 0, stream>>>(q_bf, k_bf, vt_bf, attn_bf);
  gemm_bt8<<<dim3(32, 8), 512, 0, stream>>>(attn_bf, wo_bf, (float*)d_out,
                                            4096, 2048, 2048);
}

// Round 12
// 278.058 us; speedup vs baseline: 1.1026x; 1.0037x over previous
//
#include <hip/hip_runtime.h>

// ---------------- problem constants ----------------
#define B_    2
#define Q_    2048
#define HID_  2048
#define HQ_   16
#define HKV_  4
#define D_    128
// softmax scale folded into q, in exp2 domain: D^-0.5 * log2(e)
#define QSC_  (0.08838834764831843f * 1.4426950408889634f)
#define LOG2_THETA 19.931568569324174f // log2(1e6)
// fixed softmax max: |score*log2e| <= sqrt(128)*1.4427 = 16.33 < 20 (RMSNorm'd q,k)
#define FMAX_ 20.0f

typedef unsigned short u16;
typedef __attribute__((ext_vector_type(8))) short bf16x8;
typedef __attribute__((ext_vector_type(4))) float f32x4;

__device__ __forceinline__ u16 f2bf(float x) {           // round-nearest-even
  union { float f; unsigned int u; } v; v.f = x;
  unsigned int r = v.u + 0x7FFFu + ((v.u >> 16) & 1u);
  return (u16)(r >> 16);
}
__device__ __forceinline__ u16 f2bf_t(float x) {         // truncate (hot loop)
  union { float f; unsigned int u; } v; v.f = x;
  return (u16)(v.u >> 16);
}

// async global->LDS, 16B per lane; lds must be the wave-uniform base
__device__ __forceinline__ void gl2lds16(u16* lds, const u16* g) {
  __builtin_amdgcn_global_load_lds((const __attribute__((address_space(1))) void*)g,
                                   (__attribute__((address_space(3))) void*)lds,
                                   16, 0, 0);
}

// ------- fused fp32->bf16 casts (hidden, wqkv, wo) + RoPE cos/sin table -----
#define N4_HID  2097152
#define N4_WQKV 1572864
#define N4_WO   1048576
#define N4_ALL  (N4_HID + N4_WQKV + N4_WO)     // 4718592 = 18432*256
#define NROPE   (B_ * Q_ * 64)                 // 262144  = 1024*256
__global__ __launch_bounds__(256) void cvt_all(const float* __restrict__ h,
                                               const float* __restrict__ wq,
                                               const float* __restrict__ wo,
                                               const int* __restrict__ pos,
                                               u16* __restrict__ oh,
                                               u16* __restrict__ owq,
                                               u16* __restrict__ owo,
                                               float* __restrict__ rope) {
  int i = blockIdx.x * 256 + threadIdx.x;
  if (i >= N4_ALL) {                            // RoPE table part
    int j = i - N4_ALL;                         // < NROPE
    int d = j & 63, row = j >> 6;
    float p = (float)pos[row];
    float inv = exp2f(-(float)d * (LOG2_THETA / 64.f));
    float sn, cn;
    sincosf(p * inv, &sn, &cn);
    ((float2*)rope)[j] = make_float2(cn, sn);
    return;
  }
  const float* src; u16* dst; int off;
  if (i < N4_HID)                 { src = h;  dst = oh;  off = i; }
  else if (i < N4_HID + N4_WQKV)  { src = wq; dst = owq; off = i - N4_HID; }
  else                            { src = wo; dst = owo; off = i - N4_HID - N4_WQKV; }
  float4 v = *(const float4*)(src + (size_t)off * 4);
  ushort4 o;
  o.x = f2bf(v.x); o.y = f2bf(v.y); o.z = f2bf(v.z); o.w = f2bf(v.w);
  *(ushort4*)(dst + (size_t)off * 4) = o;
}

// ------- fused QKV GEMM (256x256 8-phase) + RMSNorm + RoPE + layout ---------
// (unchanged from round 3 -- verified, bank-conflict-free)
__global__ __launch_bounds__(512) void gemm_qkv8(const u16* __restrict__ A,
                                                 const u16* __restrict__ Bw,
                                                 const float* __restrict__ rope,
                                                 const float* __restrict__ qw,
                                                 const float* __restrict__ kw,
                                                 u16* __restrict__ qb,
                                                 u16* __restrict__ kb,
                                                 u16* __restrict__ vt) {
  __shared__ __align__(16) u16 lds[65536];
  const int tid = threadIdx.x;
  const int wv = tid >> 6, lane = tid & 63;
  const int wm = wv >> 1, wn = wv & 1;             // 4M x 2N
  const int c = lane & 15, quad = lane >> 4;
  const int m0 = blockIdx.x * 256;
  const int by = blockIdx.y;
  const int n0 = by * 256;
  const int xg = ((lane & 7) ^ (lane >> 3)) * 8;   // staging source swizzle
  const int x0 = ((quad)     ^ (c & 7)) * 8;       // read swizzle, ks=0
  const int x1 = ((quad | 4) ^ (c & 7)) * 8;       // read swizzle, ks=1
  const int aoff = (wm >> 1) * 8192 + (wm & 1) * 4096 + c * 64;
  const int boff = 32768 + wn * 8192 + c * 64;
  const u16* Ag = A  + (size_t)m0 * HID_;
  const u16* Bg = Bw + (size_t)n0 * HID_;
  const int NIT = HID_ >> 7;                       // 16

#define STGQ(base, g, h, kt, buf)                                             \
  { _Pragma("unroll")                                                         \
    for (int j = 0; j < 2; ++j) {                                             \
      const int s = j * 8 + wv;                                               \
      gl2lds16(lds + (base) + (buf) * 16384 + (h) * 8192 + s * 512,           \
               (g) + (size_t)((h) * 128 + s * 8 + (lane >> 3)) * HID_         \
                   + (kt) * 64 + xg);                                         \
    } }
#define STGQ_A(h, kt, buf) STGQ(0,     Ag, h, kt, buf)
#define STGQ_B(h, kt, buf) STGQ(32768, Bg, h, kt, buf)
#define BARQ()  asm volatile("s_barrier" ::: "memory")
#define WLGQ()  { asm volatile("s_waitcnt lgkmcnt(0)" ::: "memory");          \
                  __builtin_amdgcn_sched_barrier(0); }
#define WVMQ(n) { asm volatile("s_waitcnt vmcnt(" #n ")" ::: "memory");       \
                  __builtin_amdgcn_sched_barrier(0); }
#define MMQ(MF, NF, FA, MI) {                                                 \
  acc[MF][NF] = __builtin_amdgcn_mfma_f32_16x16x32_bf16(FA[MI][0], fB[(NF)&3][0], \
                                                        acc[MF][NF], 0, 0, 0);\
  acc[MF][NF] = __builtin_amdgcn_mfma_f32_16x16x32_bf16(FA[MI][1], fB[(NF)&3][1], \
                                                        acc[MF][NF], 0, 0, 0); }

  f32x4 acc[4][8] = {};
  bf16x8 fAa[2][2], fAb[2][2], fB[4][2];

  STGQ_A(0, 0, 0); STGQ_A(1, 0, 0); STGQ_B(0, 0, 0); STGQ_B(1, 0, 0);
  STGQ_A(0, 1, 1); STGQ_B(0, 1, 1);
  WVMQ(4);
  BARQ();

#pragma unroll 1
  for (int it = 0; it < NIT; ++it) {
    const bool last = (it == NIT - 1);
    const int kt1 = 2 * it + 1, kt2 = 2 * it + 2, kt3 = 2 * it + 3;

#pragma unroll
    for (int mi = 0; mi < 2; ++mi) {
      fAa[mi][0] = *(const bf16x8*)(lds + aoff + mi * 1024 + x0);
      fAa[mi][1] = *(const bf16x8*)(lds + aoff + mi * 1024 + x1);
    }
#pragma unroll
    for (int nf = 0; nf < 4; ++nf) {
      fB[nf][0] = *(const bf16x8*)(lds + boff + nf * 1024 + x0);
      fB[nf][1] = *(const bf16x8*)(lds + boff + nf * 1024 + x1);
    }
    STGQ_A(1, kt1, 1);
    BARQ(); WLGQ();
    __builtin_amdgcn_s_setprio(1);
#pragma unroll
    for (int mi = 0; mi < 2; ++mi)
#pragma unroll
      for (int nf = 0; nf < 4; ++nf) MMQ(mi, nf, fAa, mi);
    __builtin_amdgcn_s_setprio(0);
    BARQ();

#pragma unroll
    for (int mi = 0; mi < 2; ++mi) {
      fAb[mi][0] = *(const bf16x8*)(lds + aoff + (2 + mi) * 1024 + x0);
      fAb[mi][1] = *(const bf16x8*)(lds + aoff + (2 + mi) * 1024 + x1);
    }
    STGQ_B(1, kt1, 1);
    BARQ(); WLGQ();
    __builtin_amdgcn_s_setprio(1);
#pragma unroll
    for (int mi = 0; mi < 2; ++mi)
#pragma unroll
      for (int nf = 0; nf < 4; ++nf) MMQ(2 + mi, nf, fAb, mi);
    __builtin_amdgcn_s_setprio(0);
    BARQ();

#pragma unroll
    for (int nf = 0; nf < 4; ++nf) {
      fB[nf][0] = *(const bf16x8*)(lds + boff + (4 + nf) * 1024 + x0);
      fB[nf][1] = *(const bf16x8*)(lds + boff + (4 + nf) * 1024 + x1);
    }
    if (!last) STGQ_A(0, kt2, 0);
    BARQ(); WLGQ();
    __builtin_amdgcn_s_setprio(1);
#pragma unroll
    for (int mi = 0; mi < 2; ++mi)
#pragma unroll
      for (int nf = 4; nf < 8; ++nf) MMQ(2 + mi, nf, fAb, mi);
    __builtin_amdgcn_s_setprio(0);
    BARQ();

    if (!last) STGQ_B(0, kt2, 0);
    BARQ(); WLGQ();
    __builtin_amdgcn_s_setprio(1);
#pragma unroll
    for (int mi = 0; mi < 2; ++mi)
#pragma unroll
      for (int nf = 4; nf < 8; ++nf) MMQ(mi, nf, fAa, mi);
    __builtin_amdgcn_s_setprio(0);
    if (last) { WVMQ(0); } else { WVMQ(4); }
    BARQ();

#pragma unroll
    for (int mi = 0; mi < 2; ++mi) {
      fAa[mi][0] = *(const bf16x8*)(lds + 16384 + aoff + mi * 1024 + x0);
      fAa[mi][1] = *(const bf16x8*)(lds + 16384 + aoff + mi * 1024 + x1);
    }
#pragma unroll
    for (int nf = 0; nf < 4; ++nf) {
      fB[nf][0] = *(const bf16x8*)(lds + 16384 + boff + nf * 1024 + x0);
      fB[nf][1] = *(const bf16x8*)(lds + 16384 + boff + nf * 1024 + x1);
    }
    if (!last) STGQ_A(1, kt2, 0);
    BARQ(); WLGQ();
    __builtin_amdgcn_s_setprio(1);
#pragma unroll
    for (int mi = 0; mi < 2; ++mi)
#pragma unroll
      for (int nf = 0; nf < 4; ++nf) MMQ(mi, nf, fAa, mi);
    __builtin_amdgcn_s_setprio(0);
    BARQ();

#pragma unroll
    for (int mi = 0; mi < 2; ++mi) {
      fAb[mi][0] = *(const bf16x8*)(lds + 16384 + aoff + (2 + mi) * 1024 + x0);
      fAb[mi][1] = *(const bf16x8*)(lds + 16384 + aoff + (2 + mi) * 1024 + x1);
    }
    if (!last) STGQ_B(1, kt2, 0);
    BARQ(); WLGQ();
    __builtin_amdgcn_s_setprio(1);
#pragma unroll
    for (int mi = 0; mi < 2; ++mi)
#pragma unroll
      for (int nf = 0; nf < 4; ++nf) MMQ(2 + mi, nf, fAb, mi);
    __builtin_amdgcn_s_setprio(0);
    BARQ();

#pragma unroll
    for (int nf = 0; nf < 4; ++nf) {
      fB[nf][0] = *(const bf16x8*)(lds + 16384 + boff + (4 + nf) * 1024 + x0);
      fB[nf][1] = *(const bf16x8*)(lds + 16384 + boff + (4 + nf) * 1024 + x1);
    }
    if (!last) STGQ_A(0, kt3, 1);
    BARQ(); WLGQ();
    __builtin_amdgcn_s_setprio(1);
#pragma unroll
    for (int mi = 0; mi < 2; ++mi)
#pragma unroll
      for (int nf = 4; nf < 8; ++nf) MMQ(2 + mi, nf, fAb, mi);
    __builtin_amdgcn_s_setprio(0);
    BARQ();

    if (!last) STGQ_B(0, kt3, 1);
    BARQ(); WLGQ();
    __builtin_amdgcn_s_setprio(1);
#pragma unroll
    for (int mi = 0; mi < 2; ++mi)
#pragma unroll
      for (int nf = 4; nf < 8; ++nf) MMQ(mi, nf, fAa, mi);
    __builtin_amdgcn_s_setprio(0);
    if (last) { WVMQ(0); } else { WVMQ(4); }
    BARQ();
  }

  const int h = by * 2 + wn;
  if (h < 20) {
    const bool isq = h < 16;
    const float* w = isq ? qw : kw;
    const float osc = isq ? QSC_ : 1.f;
    float wl[8];
#pragma unroll
    for (int nf = 0; nf < 8; ++nf) wl[nf] = w[nf * 16 + c];
    u16* dstbuf = isq ? qb : kb;
    const int hbase = isq ? h : (h - 16);
    const int nheads = isq ? HQ_ : HKV_;
    u16* lw = lds + wv * 4224;                   // 32 rows x stride 132
#pragma unroll
    for (int pass = 0; pass < 2; ++pass) {
#pragma unroll
      for (int mi = 0; mi < 2; ++mi) {
        const int mf = pass * 2 + mi;
#pragma unroll
        for (int r = 0; r < 4; ++r) {
          const int row = m0 + wm * 64 + mf * 16 + quad * 4 + r;
          const int q = row & (Q_ - 1), b = row >> 11;
          float ss = 0.f;
#pragma unroll
          for (int nf = 0; nf < 8; ++nf) ss += acc[mf][nf][r] * acc[mf][nf][r];
          ss += __shfl_xor(ss, 1); ss += __shfl_xor(ss, 2);
          ss += __shfl_xor(ss, 4); ss += __shfl_xor(ss, 8);
          const float rn = rsqrtf(ss * (1.f / 128.f) + 1e-6f) * osc;
          u16* lrow = lw + (mi * 16 + quad * 4 + r) * 132;
#pragma unroll
          for (int ni = 0; ni < 4; ni++) {
            float2 cssn = *(const float2*)(rope +
                ((size_t)(b * Q_ + q) * 64 + ni * 16 + c) * 2);
            float x1 = acc[mf][ni][r]     * wl[ni]     * rn;
            float x2 = acc[mf][ni + 4][r] * wl[ni + 4] * rn;
            lrow[ni * 16 + c]       = f2bf(x1 * cssn.x - x2 * cssn.y);
            lrow[(ni + 4) * 16 + c] = f2bf(x2 * cssn.x + x1 * cssn.y);
          }
        }
      }
#pragma unroll
      for (int itr = 0; itr < 8; ++itr) {
        const int rl = itr * 4 + quad;           // 0..31
        const int rowg = m0 + wm * 64 + pass * 32 + rl;
        const int q = rowg & (Q_ - 1), b = rowg >> 11;
        u16* dst = dstbuf + (((size_t)(b * nheads) + hbase) * Q_ + q) * D_ + c * 8;
        *(bf16x8*)dst = *(const bf16x8*)(lw + rl * 132 + c * 8);
      }
    }
  } else {
    const int hk = h - 20;
    const int bb = m0 >> 11;
    const int q0w = (m0 & (Q_ - 1)) + wm * 64;
    u16* lw = lds + wv * 4352;                   // 64 d-rows x stride 68
#pragma unroll
    for (int pass = 0; pass < 2; ++pass) {
#pragma unroll
      for (int nfl = 0; nfl < 4; ++nfl) {
        const int nf = pass * 4 + nfl;
#pragma unroll
        for (int mf = 0; mf < 4; ++mf) {
          short4 pv;
          pv.x = (short)f2bf(acc[mf][nf][0]); pv.y = (short)f2bf(acc[mf][nf][1]);
          pv.z = (short)f2bf(acc[mf][nf][2]); pv.w = (short)f2bf(acc[mf][nf][3]);
          *(short4*)(lw + (nfl * 16 + c) * 68 + mf * 16 + quad * 4) = pv;
        }
      }
#pragma unroll
      for (int itr = 0; itr < 8; ++itr) {
        const int dl = itr * 8 + (lane >> 3);    // 0..63
        const int d = pass * 64 + dl;
        u16* dst = vt + (((size_t)(bb * HKV_) + hk) * D_ + d) * Q_ +
                   q0w + (lane & 7) * 8;
        *(bf16x8*)dst = *(const bf16x8*)(lw + dl * 68 + (lane & 7) * 8);
      }
    }
  }
#undef STGQ
#undef STGQ_A
#undef STGQ_B
#undef BARQ
#undef WLGQ
#undef WVMQ
#undef MMQ
}

// ------------- bf16 GEMM, 128x256 tile, 8-phase counted-vmcnt schedule ------
// (unchanged from round 5 -- verified; grid 256 = 100% CU fill)
__global__ __launch_bounds__(512) void gemm_bt8(const u16* __restrict__ A,
                                                const u16* __restrict__ Bw,
                                                float* __restrict__ C,
                                                int M, int N, int K) {
  __shared__ __align__(16) u16 lds[49152];
  const int tid = threadIdx.x;
  const int wv = tid >> 6, lane = tid & 63;
  const int wm = wv >> 2, wn = wv & 3;             // 2M x 4N
  const int c = lane & 15, quad = lane >> 4;
  const int m0 = blockIdx.x * 128, n0 = blockIdx.y * 256;
  const int xg = ((lane & 7) ^ (lane >> 3)) * 8;   // staging source swizzle
  const int x0 = ((quad)     ^ (c & 7)) * 8;       // read swizzle, ks=0
  const int x1 = ((quad | 4) ^ (c & 7)) * 8;       // read swizzle, ks=1
  const int aoff = wm * 4096 + c * 64;                                  // +buf*8192
  const int boff = 16384 + (wn >> 1) * 8192 + (wn & 1) * 4096 + c * 64; // +buf*16384
  const u16* Ag = A  + (size_t)m0 * K;
  const u16* Bg = Bw + (size_t)n0 * K;
  const int NIT = K >> 7;                          // 16

#define STA2(h, kt, buf)                                                      \
  gl2lds16(lds + (buf) * 8192 + (h) * 4096 + wv * 512,                        \
           Ag + (size_t)((h) * 64 + wv * 8 + (lane >> 3)) * K + (kt) * 64 + xg);
#define STB2(h, kt, buf)                                                      \
  { _Pragma("unroll")                                                         \
    for (int j = 0; j < 2; ++j)                                               \
      gl2lds16(lds + 16384 + (buf) * 16384 + (h) * 8192 + j * 4096 + wv * 512,\
               Bg + (size_t)((h) * 128 + j * 64 + wv * 8 + (lane >> 3)) * K   \
                   + (kt) * 64 + xg); }
#define BAR8()  asm volatile("s_barrier" ::: "memory")
#define WLG8()  { asm volatile("s_waitcnt lgkmcnt(0)" ::: "memory");          \
                  __builtin_amdgcn_sched_barrier(0); }
#define WVM8(n) { asm volatile("s_waitcnt vmcnt(" #n ")" ::: "memory");       \
                  __builtin_amdgcn_sched_barrier(0); }
#define MM2(MF, NF, FA, FB, MI, NI) {                                         \
  acc[MF][NF] = __builtin_amdgcn_mfma_f32_16x16x32_bf16(FA[MI][0], FB[NI][0], \
                                                        acc[MF][NF], 0, 0, 0);\
  acc[MF][NF] = __builtin_amdgcn_mfma_f32_16x16x32_bf16(FA[MI][1], FB[NI][1], \
                                                        acc[MF][NF], 0, 0, 0); }

  f32x4 acc[4][4] = {};
  bf16x8 fAa[2][2], fAb[2][2], fBa[2][2], fBb[2][2];

  // prologue: c0 -> buf0 (6 loads), c1 -> buf1 (6); wait c0, leave c1 flying
  STA2(0, 0, 0); STA2(1, 0, 0); STB2(0, 0, 0); STB2(1, 0, 0);
  STA2(0, 1, 1); STA2(1, 1, 1); STB2(0, 1, 1); STB2(1, 1, 1);
  WVM8(6);
  BAR8();

#pragma unroll 1
  for (int it = 0; it < NIT; ++it) {
    const bool last = (it == NIT - 1);
    const int kt2 = 2 * it + 2, kt3 = 2 * it + 3;

    // ================= first half: compute K-tile 2it from buf0 ===========
#pragma unroll
    for (int mi = 0; mi < 2; ++mi) {
      fAa[mi][0] = *(const bf16x8*)(lds + aoff + mi * 1024 + x0);
      fAa[mi][1] = *(const bf16x8*)(lds + aoff + mi * 1024 + x1);
      fBa[mi][0] = *(const bf16x8*)(lds + boff + mi * 1024 + x0);
      fBa[mi][1] = *(const bf16x8*)(lds + boff + mi * 1024 + x1);
    }
    BAR8(); WLG8();
    __builtin_amdgcn_s_setprio(1);
    MM2(0, 0, fAa, fBa, 0, 0); MM2(0, 1, fAa, fBa, 0, 1);
    MM2(1, 0, fAa, fBa, 1, 0); MM2(1, 1, fAa, fBa, 1, 1);
    __builtin_amdgcn_s_setprio(0);
    BAR8();

#pragma unroll
    for (int mi = 0; mi < 2; ++mi) {
      fAb[mi][0] = *(const bf16x8*)(lds + aoff + (2 + mi) * 1024 + x0);
      fAb[mi][1] = *(const bf16x8*)(lds + aoff + (2 + mi) * 1024 + x1);
    }
    BAR8(); WLG8();
    __builtin_amdgcn_s_setprio(1);
    MM2(2, 0, fAb, fBa, 0, 0); MM2(2, 1, fAb, fBa, 0, 1);
    MM2(3, 0, fAb, fBa, 1, 0); MM2(3, 1, fAb, fBa, 1, 1);
    __builtin_amdgcn_s_setprio(0);
    BAR8();

#pragma unroll
    for (int ni = 0; ni < 2; ++ni) {
      fBb[ni][0] = *(const bf16x8*)(lds + boff + (2 + ni) * 1024 + x0);
      fBb[ni][1] = *(const bf16x8*)(lds + boff + (2 + ni) * 1024 + x1);
    }
    if (!last) { STA2(0, kt2, 0); STA2(1, kt2, 0); }
    BAR8(); WLG8();
    __builtin_amdgcn_s_setprio(1);
    MM2(2, 2, fAb, fBb, 0, 0); MM2(2, 3, fAb, fBb, 0, 1);
    MM2(3, 2, fAb, fBb, 1, 0); MM2(3, 3, fAb, fBb, 1, 1);
    __builtin_amdgcn_s_setprio(0);
    BAR8();

    if (!last) { STB2(0, kt2, 0); STB2(1, kt2, 0); }
    BAR8(); WLG8();
    __builtin_amdgcn_s_setprio(1);
    MM2(0, 2, fAa, fBb, 0, 0); MM2(0, 3, fAa, fBb, 0, 1);
    MM2(1, 2, fAa, fBb, 1, 0); MM2(1, 3, fAa, fBb, 1, 1);
    __builtin_amdgcn_s_setprio(0);
    if (last) { WVM8(0); } else { WVM8(6); }     // c1 fully landed past here
    BAR8();

    // ================= second half: compute K-tile 2it+1 from buf1 =========
#pragma unroll
    for (int mi = 0; mi < 2; ++mi) {
      fAa[mi][0] = *(const bf16x8*)(lds + 8192 + aoff + mi * 1024 + x0);
      fAa[mi][1] = *(const bf16x8*)(lds + 8192 + aoff + mi * 1024 + x1);
      fBa[mi][0] = *(const bf16x8*)(lds + 16384 + boff + mi * 1024 + x0);
      fBa[mi][1] = *(const bf16x8*)(lds + 16384 + boff + mi * 1024 + x1);
    }
    BAR8(); WLG8();
    __builtin_amdgcn_s_setprio(1);
    MM2(0, 0, fAa, fBa, 0, 0); MM2(0, 1, fAa, fBa, 0, 1);
    MM2(1, 0, fAa, fBa, 1, 0); MM2(1, 1, fAa, fBa, 1, 1);
    __builtin_amdgcn_s_setprio(0);
    BAR8();

#pragma unroll
    for (int mi = 0; mi < 2; ++mi) {
      fAb[mi][0] = *(const bf16x8*)(lds + 8192 + aoff + (2 + mi) * 1024 + x0);
      fAb[mi][1] = *(const bf16x8*)(lds + 8192 + aoff + (2 + mi) * 1024 + x1);
    }
    BAR8(); WLG8();
    __builtin_amdgcn_s_setprio(1);
    MM2(2, 0, fAb, fBa, 0, 0); MM2(2, 1, fAb, fBa, 0, 1);
    MM2(3, 0, fAb, fBa, 1, 0); MM2(3, 1, fAb, fBa, 1, 1);
    __builtin_amdgcn_s_setprio(0);
    BAR8();

#pragma unroll
    for (int ni = 0; ni < 2; ++ni) {
      fBb[ni][0] = *(const bf16x8*)(lds + 16384 + boff + (2 + ni) * 1024 + x0);
      fBb[ni][1] = *(const bf16x8*)(lds + 16384 + boff + (2 + ni) * 1024 + x1);
    }
    if (!last) { STA2(0, kt3, 1); STA2(1, kt3, 1); }
    BAR8(); WLG8();
    __builtin_amdgcn_s_setprio(1);
    MM2(2, 2, fAb, fBb, 0, 0); MM2(2, 3, fAb, fBb, 0, 1);
    MM2(3, 2, fAb, fBb, 1, 0); MM2(3, 3, fAb, fBb, 1, 1);
    __builtin_amdgcn_s_setprio(0);
    BAR8();

    if (!last) { STB2(0, kt3, 1); STB2(1, kt3, 1); }
    BAR8(); WLG8();
    __builtin_amdgcn_s_setprio(1);
    MM2(0, 2, fAa, fBb, 0, 0); MM2(0, 3, fAa, fBb, 0, 1);
    MM2(1, 2, fAa, fBb, 1, 0); MM2(1, 3, fAa, fBb, 1, 1);
    __builtin_amdgcn_s_setprio(0);
    if (last) { WVM8(0); } else { WVM8(6); }     // c2 fully landed past here
    BAR8();
  }

  // ---- epilogue: fp32 C write --------------------------------------------
  const int crow = m0 + wm * 64 + quad * 4;
  const int ccol = n0 + wn * 64 + c;
#pragma unroll
  for (int mf = 0; mf < 4; ++mf)
#pragma unroll
    for (int nf = 0; nf < 4; ++nf)
#pragma unroll
      for (int r = 0; r < 4; ++r)
        C[(size_t)(crow + mf * 16 + r) * N + ccol + nf * 16] = acc[mf][nf][r];
#undef STA2
#undef STB2
#undef BAR8
#undef WLG8
#undef WVM8
#undef MM2
}

// ------ flash attention, causal, GQA; fixed-max softmax (RMSNorm bound) -----
// v8 = round-11 session-best body (v2+setprio) with T1 XCD-aware block
// mapping: flat 1D grid of 512; flat%8 (= XCD under round-robin dispatch)
// selects one (b,hk) pair -- that XCD's L2 then caches the pair's K+V (1MB)
// and Q (2MB), so KV streams from HBM once per XCD instead of 4x (one per
// query head). Pure index remap; correctness independent of XCD mapping.
__global__ __launch_bounds__(256) void attn_fwd(const u16* __restrict__ qb,
                                                const u16* __restrict__ kb,
                                                const u16* __restrict__ vt,
                                                u16* __restrict__ ob) {
  __shared__ __align__(16) u16 lds[2 * 8192 + 2 * 8192 + 4608];  // 73 KB
  // K[b] @ b*8192 ; V[b] @ 16384 + b*8192 ; P @ 32768 ; bounce reuses K0/K1
  const int flat = blockIdx.x;               // 0..511, dispatch order = flat
  const int e = flat & 7, j = flat >> 3;     // e -> XCD; j -> work within XCD
  const int b = e >> 2, hk = e & 3;          // one (b,hk) per XCD
  const int h = hk * 4 + (j & 3);            // 4 query heads sharing this KV
  const int p = j >> 2;                      // strip pair id 0..15
  const int tid = threadIdx.x, wave = tid >> 6, lane = tid & 63;
  const int c = lane & 15, quad = lane >> 4;
  const int lr = lane >> 2, lp = lane & 3;
  const int lpg = (lp + 4 - ((lr >> 1) & 3)) & 3;
  const int swq = ((quad + (c >> 1)) & 3) * 8;
  const u16* qg = qb + ((size_t)b * HQ_ + h) * (size_t)Q_ * D_;
  const u16* kg = kb + ((size_t)b * HKV_ + hk) * (size_t)Q_ * D_;
  const u16* vg = vt + ((size_t)b * HKV_ + hk) * (size_t)D_ * Q_;
  u16* Pw = lds + 32768 + wave * 1152;
  u16* Bw = lds + wave * 2176;

#define ASTAGE(KT, BS)                                                        \
  { _Pragma("unroll")                                                         \
    for (int i = 0; i < 4; i++) {                                             \
      gl2lds16(lds + (BS) * 8192 + (size_t)(i * 256 + wave * 64) * 8,         \
               kg + ((size_t)(KT) * 64 + wave * 16 + lr) * D_ + i * 32 + lpg * 8); \
      int d = (i & 1) * 64 + wave * 16 + lr;                                  \
      gl2lds16(lds + 16384 + (BS) * 8192 + (size_t)(i * 256 + wave * 64) * 8, \
               vg + (size_t)d * Q_ + (KT) * 64 + (i >> 1) * 32 + lpg * 8);    \
    } }

#pragma unroll 1
  for (int tp = 0; tp < 2; tp++) {
    const int t = tp ? (31 - p) : p;
    const int q0 = t * 64;
    const int qrow = q0 + wave * 16 + c;
    bf16x8 qf[4];
#pragma unroll
    for (int kk = 0; kk < 4; kk++)
      qf[kk] = *(const bf16x8*)(qg + (size_t)qrow * D_ + kk * 32 + quad * 8);
    f32x4 Oa[8] = {};
    float l_acc = 0.f;

    if (tp) __syncthreads();       // strip-0 bounce reads done before refill
    ASTAGE(0, 0);

#pragma unroll 1
    for (int kt = 0; kt <= t; kt++) {
      const int bs = kt & 1;
      __syncthreads();             // DMA(kt) landed + all waves joined
      if (kt < t) ASTAGE(kt + 1, bs ^ 1);
      const u16* Ksb = lds + bs * 8192;
      const u16* Vsb = lds + 16384 + bs * 8192;
      f32x4 S[4];
      __builtin_amdgcn_s_setprio(1);
#pragma unroll
      for (int n = 0; n < 4; n++) {
        f32x4 a = {-FMAX_, -FMAX_, -FMAX_, -FMAX_};   // bias folded into C
#pragma unroll
        for (int kk = 0; kk < 4; kk++) {
          bf16x8 kf = *(const bf16x8*)(Ksb + kk * 2048 + (n * 16 + c) * 32 + swq);
          a = __builtin_amdgcn_mfma_f32_16x16x32_bf16(kf, qf[kk], a, 0, 0, 0);
        }
        S[n] = a;
      }
      __builtin_amdgcn_s_setprio(0);
      if (kt == t) {
#pragma unroll
        for (int n = 0; n < 4; n++)
#pragma unroll
          for (int r = 0; r < 4; r++) {
            int key = kt * 64 + n * 16 + quad * 4 + r;
            if (key > qrow) S[n][r] = -1e9f;          // exp2 -> 0
          }
      }
#pragma unroll
      for (int n = 0; n < 4; n++) {
        float p0 = __builtin_amdgcn_exp2f(S[n][0]);
        float p1 = __builtin_amdgcn_exp2f(S[n][1]);
        float p2 = __builtin_amdgcn_exp2f(S[n][2]);
        float p3 = __builtin_amdgcn_exp2f(S[n][3]);
        l_acc += (p0 + p1) + (p2 + p3);
        short4 pk;
        pk.x = (short)f2bf_t(p0); pk.y = (short)f2bf_t(p1);
        pk.z = (short)f2bf_t(p2); pk.w = (short)f2bf_t(p3);
        *(short4*)(Pw + c * 72 + n * 16 + quad * 4) = pk;
      }
      bf16x8 pf[2];
#pragma unroll
      for (int kk2 = 0; kk2 < 2; kk2++)
        pf[kk2] = *(const bf16x8*)(Pw + c * 72 + kk2 * 32 + quad * 8);
      __builtin_amdgcn_s_setprio(1);
#pragma unroll
      for (int md = 0; md < 8; md++)
#pragma unroll
        for (int kk2 = 0; kk2 < 2; kk2++) {
          bf16x8 vf = *(const bf16x8*)(Vsb + kk2 * 4096 + (md * 16 + c) * 32 + swq);
          Oa[md] = __builtin_amdgcn_mfma_f32_16x16x32_bf16(vf, pf[kk2], Oa[md], 0, 0, 0);
        }
      __builtin_amdgcn_s_setprio(0);
    }
    // strip epilogue: reduce l across quads, normalize, transpose, store
    float l_row = l_acc;
    l_row += __shfl_xor(l_row, 16);
    l_row += __shfl_xor(l_row, 32);
    __syncthreads();    // all waves done with K/V reads; K region = bounce
    const float invl = 1.f / l_row;
#pragma unroll
    for (int md = 0; md < 8; md++) {
      short4 ok;
      ok.x = (short)f2bf(Oa[md][0] * invl); ok.y = (short)f2bf(Oa[md][1] * invl);
      ok.z = (short)f2bf(Oa[md][2] * invl); ok.w = (short)f2bf(Oa[md][3] * invl);
      *(short4*)(Bw + c * 136 + md * 16 + quad * 4) = ok;
    }
    const int orow = q0 + wave * 16 + lr;
#pragma unroll
    for (int tt = 0; tt < 4; tt++) {
      bf16x8 ov = *(const bf16x8*)(Bw + lr * 136 + lp * 32 + tt * 8);
      *(bf16x8*)(ob + ((size_t)(b * Q_ + orow) * HQ_ + h) * D_ + lp * 32 + tt * 8) = ov;
    }
  }
#undef ASTAGE
}

// ---------------- launcher ----------------
extern "C" void kernel_launch(void* const* d_in, const int* in_sizes, int n_in,
                              void* d_out, int out_size, void* d_ws, size_t ws_size,
                              hipStream_t stream) {
  const int*   positions = (const int*)  d_in[0];
  const float* hidden    = (const float*)d_in[1];
  const float* wqkv      = (const float*)d_in[4];
  const float* wo        = (const float*)d_in[5];
  const float* qnw       = (const float*)d_in[6];
  const float* knw       = (const float*)d_in[7];
  char* ws = (char*)d_ws;
  u16*   hid_bf  = (u16*)(ws);                     // 16,777,216
  u16*   wqkv_bf = (u16*)(ws + 16777216);          // 12,582,912
  u16*   wo_bf   = (u16*)(ws + 29360128);          //  8,388,608
  u16*   q_bf    = (u16*)(ws + 37748736);          // 16,777,216
  u16*   k_bf    = (u16*)(ws + 54525952);          //  4,194,304
  u16*   vt_bf   = (u16*)(ws + 58720256);          //  4,194,304
  float* rope    = (float*)(ws + 62914560);        //  2,097,152
  u16*   attn_bf = hid_bf;                         // alias: dead after gemm_qkv8

  cvt_all<<<19456, 256, 0, stream>>>(hidden, wqkv, wo, positions,
                                     hid_bf, wqkv_bf, wo_bf, rope);
  gemm_qkv8<<<dim3(16, 12), 512, 0, stream>>>(hid_bf, wqkv_bf, rope, qnw, knw,
                                              q_bf, k_bf, vt_bf);
  attn_fwd<<<dim3(512, 1, 1), 256, 0, stream>>>(q_bf, k_bf, vt_bf, attn_bf);
  gemm_bt8<<<dim3(32, 8), 512, 0, stream>>>(attn_bf, wo_bf, (float*)d_out,
                                            4096, 2048, 2048);
}